// Round 5
// baseline (266.194 us; speedup 1.0000x reference)
//
#include <hip/hip_runtime.h>
#include <hip/hip_bf16.h>
#include <cstdint>
#include <cstddef>

#define Hh 8
#define DIN 512
#define CONVD 640
#define DPROJ 1168
#define NTOK 8192
#define DIM 256

typedef __attribute__((ext_vector_type(8))) short short8;
typedef __attribute__((ext_vector_type(4))) float f32x4;

static __device__ __forceinline__ float sigmoidf_(float x) { return 1.f / (1.f + expf(-x)); }
static __device__ __forceinline__ unsigned short f2b(float f) {
  __hip_bfloat16 h = __float2bfloat16(f);
  return *(unsigned short*)&h;
}
static __device__ __forceinline__ float b2f(unsigned short u) {
  union { unsigned int i; float f; } cv; cv.i = ((unsigned int)u) << 16; return cv.f;
}
// async global->LDS, 16B per lane. LDS dest must be linear in lane order.
static __device__ __forceinline__ void gll16(const void* g, void* l) {
  __builtin_amdgcn_global_load_lds((const __attribute__((address_space(1))) void*)g,
                                   (__attribute__((address_space(3))) void*)l, 16, 0, 0);
}

// ---------------------------------------------------------------------------
// K0: merged conversions. blocks <4096: x fp32->bf16 (8/thread).
// blocks >=4096: weights fp32->bf16 + bias concat (4/thread).
__global__ __launch_bounds__(256) void k_cvt(
    const float* __restrict__ wfx, const float* __restrict__ wx, const float* __restrict__ outw,
    const float* __restrict__ inw, const float* __restrict__ how,
    const float* __restrict__ bfx, const float* __restrict__ bx,
    const float* __restrict__ x,
    unsigned short* __restrict__ wcat, unsigned short* __restrict__ outwb,
    unsigned short* __restrict__ inwb, unsigned short* __restrict__ howb,
    float* __restrict__ bcat, unsigned short* __restrict__ xb) {
  const int blk = blockIdx.x;
  if (blk < 4096) {  // x: 4*8192*256 = 8,388,608 elems
    const int e = (blk * 256 + threadIdx.x) * 8;
    float4 v0 = *(const float4*)(x + e);
    float4 v1 = *(const float4*)(x + e + 4);
    short8 o;
    o[0] = (short)f2b(v0.x); o[1] = (short)f2b(v0.y);
    o[2] = (short)f2b(v0.z); o[3] = (short)f2b(v0.w);
    o[4] = (short)f2b(v1.x); o[5] = (short)f2b(v1.y);
    o[6] = (short)f2b(v1.z); o[7] = (short)f2b(v1.w);
    *(short8*)(xb + e) = o;
    return;
  }
  const int e = ((blk - 4096) * 256 + threadIdx.x) * 4;
  if (e >= 1253376) {
    const int i = e - 1253376;  // 0..1023
    float4 v;
    if (i < 512) v = *(const float4*)(bfx + i);
    else         v = *(const float4*)(bx + (i - 512));
    *(float4*)(bcat + i) = v;
    return;
  }
  const float* src; unsigned short* dst; int i;
  if (e < 131072)        { i = e;           src = wfx;  dst = wcat; }
  else if (e < 262144)   { i = e - 131072;  src = wx;   dst = wcat + 131072; }
  else if (e < 393216)   { i = e - 262144;  src = outw; dst = outwb; }
  else if (e < 991232)   { i = e - 393216;  src = inw;  dst = inwb; }
  else                   { i = e - 991232;  src = how;  dst = howb; }
  float4 v = *(const float4*)(src + i);
  ushort4 o;
  o.x = f2b(v.x); o.y = f2b(v.y); o.z = f2b(v.z); o.w = f2b(v.w);
  *(ushort4*)(dst + i) = o;
}

// ---------------------------------------------------------------------------
// K1: fused front GEMM + softmax + st-partial. Block = 128 tokens x 1 head.
// Cols of the GEMM tile = [fx_h (64) | xm_h (64)] (B rows h*64.. and 512+h*64..).
// After GEMM: scores+softmax for head h, sw -> swb (global) + swT (LDS),
// fx -> fxT (LDS transpose), st_partial = sw^T @ fx -> atomicAdd into st_part,
// snorm via ones-MFMA -> sn_part. cb (fx matrix) is never materialized.
__global__ __launch_bounds__(256) void k_front(
    const unsigned short* __restrict__ xb, const unsigned short* __restrict__ wcat,
    const float* __restrict__ bcat, const float* __restrict__ Wslice,
    const float* __restrict__ bslice, const float* __restrict__ temperature,
    unsigned short* __restrict__ swb, float* __restrict__ st_part,
    float* __restrict__ sn_part) {
  __shared__ unsigned short lds[34816];  // staging 2x(As8K+Bs8K)=64KB; then Cs[128][136]+swT[64][136]+fxT[64][136]
  const int tid = threadIdx.x;
  const int m0 = blockIdx.x * 128;
  const int h = blockIdx.y;
  const int w = tid >> 6, lane = tid & 63;
  const int l15 = lane & 15, kq = lane >> 4;
  const int wm = (w & 1) * 64, wn = (w >> 1) * 64;
  const int bbase = (wn == 0) ? h * 64 : 512 + h * 64;
  float bs[4];
#pragma unroll
  for (int j = 0; j < 4; ++j) bs[j] = bcat[bbase + j * 16 + l15];
  f32x4 acc[4][4];
#pragma unroll
  for (int i = 0; i < 4; ++i)
#pragma unroll
    for (int j = 0; j < 4; ++j) acc[i][j] = (f32x4){0.f, 0.f, 0.f, 0.f};

  // staging: coalesced (row-contiguous), XOR-swizzled source chunk.
  auto stage = [&](int buf, int kt) {
    unsigned short* As = lds + buf * 8192;
    unsigned short* Bs = lds + 16384 + buf * 8192;
#pragma unroll
    for (int i = 0; i < 4; ++i) {
      const int c = tid + 256 * i;          // 0..1023
      const int m = c >> 3, kb = c & 7;
      const int kbs = (kb ^ (m & 7)) * 8;   // swizzled source chunk (same line)
      gll16(&xb[(size_t)(m0 + m) * 256 + kt + kbs], &As[c * 8]);
      const int wr = (m < 64) ? (h * 64 + m) : (448 + h * 64 + m);
      gll16(&wcat[(size_t)wr * 256 + kt + kbs], &Bs[c * 8]);
    }
  };

  stage(0, 0);
  __syncthreads();  // vmcnt(0) drain: buf0 ready
  int buf = 0;
  for (int t = 0; t < 4; ++t) {
    if (t < 3) stage(buf ^ 1, (t + 1) * 64);  // prefetch next K-slab
    const unsigned short* As = lds + buf * 8192;
    const unsigned short* Bs = lds + 16384 + buf * 8192;
#pragma unroll
    for (int kw = 0; kw < 2; ++kw) {
      short8 af[4], bfr[4];
#pragma unroll
      for (int i = 0; i < 4; ++i) {
        const int rm = wm + i * 16 + l15;
        af[i]  = *(const short8*)&As[rm * 64 + ((kw * 32 + kq * 8) ^ ((rm & 7) << 3))];
        const int rn = wn + i * 16 + l15;
        bfr[i] = *(const short8*)&Bs[rn * 64 + ((kw * 32 + kq * 8) ^ ((rn & 7) << 3))];
      }
#pragma unroll
      for (int i = 0; i < 4; ++i)
#pragma unroll
        for (int j = 0; j < 4; ++j)
          acc[i][j] = __builtin_amdgcn_mfma_f32_16x16x32_bf16(af[i], bfr[j], acc[i][j], 0, 0, 0);
    }
    __syncthreads();
    buf ^= 1;
  }
  // epilogue: C (+bias) -> Cs [128][136]. cols 0..63 = fx_h, 64..127 = xm_h.
  unsigned short* Cs = lds;
#pragma unroll
  for (int i = 0; i < 4; ++i)
#pragma unroll
    for (int j = 0; j < 4; ++j)
#pragma unroll
      for (int r = 0; r < 4; ++r) {
        const int m = wm + i * 16 + kq * 4 + r;
        const int n = wn + j * 16 + l15;
        Cs[m * 136 + n] = f2b(acc[i][j][r] + bs[j]);
      }
  __syncthreads();

  // ---- scores for head h: score = xm_h @ Wslice^T ----
  short8 sbfr[2][4];
#pragma unroll
  for (int kt = 0; kt < 2; ++kt)
#pragma unroll
    for (int j = 0; j < 4; ++j) {
      const float* wp = Wslice + (j * 16 + l15) * 64 + kt * 32 + kq * 8;
      short8 t;
#pragma unroll
      for (int u = 0; u < 8; ++u) t[u] = (short)f2b(wp[u]);
      sbfr[kt][j] = t;
    }
  float sbs[4];
#pragma unroll
  for (int j = 0; j < 4; ++j) sbs[j] = bslice[j * 16 + l15];
  f32x4 sacc[2][4];
#pragma unroll
  for (int i = 0; i < 2; ++i)
#pragma unroll
    for (int j = 0; j < 4; ++j) sacc[i][j] = (f32x4){0.f, 0.f, 0.f, 0.f};
#pragma unroll
  for (int kt = 0; kt < 2; ++kt) {
    short8 af[2];
#pragma unroll
    for (int i = 0; i < 2; ++i)
      af[i] = *(const short8*)&Cs[(w * 32 + i * 16 + l15) * 136 + 64 + kt * 32 + kq * 8];
#pragma unroll
    for (int i = 0; i < 2; ++i)
#pragma unroll
      for (int j = 0; j < 4; ++j)
        sacc[i][j] = __builtin_amdgcn_mfma_f32_16x16x32_bf16(af[i], sbfr[kt][j], sacc[i][j], 0, 0, 0);
  }
  __syncthreads();  // all reads of Cs xm-region done

  unsigned short* swT = lds + 17408;  // [g=64][136] (n up to 128)
  unsigned short* fxT = lds + 26112;  // [p=64][136]
  // ---- softmax (overwrite xm region of Cs with sw, + transposed swT) ----
  const float invt = 1.f / fmaxf(temperature[h], 1e-6f);
#pragma unroll
  for (int i = 0; i < 2; ++i)
#pragma unroll
    for (int r = 0; r < 4; ++r) {
      float v[4];
      float m = -1e30f;
#pragma unroll
      for (int j = 0; j < 4; ++j) { v[j] = (sacc[i][j][r] + sbs[j]) * invt; m = fmaxf(m, v[j]); }
#pragma unroll
      for (int off = 8; off; off >>= 1) m = fmaxf(m, __shfl_xor(m, off));
      float s = 0.f;
#pragma unroll
      for (int j = 0; j < 4; ++j) { v[j] = expf(v[j] - m); s += v[j]; }
#pragma unroll
      for (int off = 8; off; off >>= 1) s += __shfl_xor(s, off);
      const float inv = 1.f / s;
      const int row = w * 32 + i * 16 + kq * 4 + r;
#pragma unroll
      for (int j = 0; j < 4; ++j) {
        const unsigned short us = f2b(v[j] * inv);
        Cs[row * 136 + 64 + j * 16 + l15] = us;       // row-major for swb write
        swT[(j * 16 + l15) * 136 + row] = us;         // transposed for st MFMA
      }
    }
  // ---- fx transpose: Cs cols 0..63 -> fxT[p][n] ----
#pragma unroll
  for (int i = 0; i < 4; ++i) {
    const int c = tid + 256 * i;          // 1024 = 128 n x 8 p-chunks
    const int n = c >> 3, pc = c & 7;
    const short8 t = *(const short8*)&Cs[n * 136 + pc * 8];
#pragma unroll
    for (int u = 0; u < 8; ++u) fxT[(pc * 8 + u) * 136 + n] = (unsigned short)t[u];
  }
  __syncthreads();

  // ---- st partial: st[g][p] = sum_n sw[n][g]*fx[n][p]; snorm via ones ----
  short8 ones;
#pragma unroll
  for (int u = 0; u < 8; ++u) ones[u] = (short)0x3F80;  // bf16 1.0
  f32x4 st_acc[4];
  f32x4 accO = (f32x4){0.f, 0.f, 0.f, 0.f};
#pragma unroll
  for (int j = 0; j < 4; ++j) st_acc[j] = (f32x4){0.f, 0.f, 0.f, 0.f};
#pragma unroll
  for (int kt = 0; kt < 4; ++kt) {
    const short8 af = *(const short8*)&swT[(w * 16 + l15) * 136 + kt * 32 + kq * 8];
#pragma unroll
    for (int j = 0; j < 4; ++j) {
      const short8 bf = *(const short8*)&fxT[(j * 16 + l15) * 136 + kt * 32 + kq * 8];
      st_acc[j] = __builtin_amdgcn_mfma_f32_16x16x32_bf16(af, bf, st_acc[j], 0, 0, 0);
    }
    accO = __builtin_amdgcn_mfma_f32_16x16x32_bf16(af, ones, accO, 0, 0, 0);
  }

  // ---- swb write (coalesced) ----
  const int bidx = m0 >> 13, nb = m0 & (NTOK - 1);
  const int bh = bidx * 8 + h;
#pragma unroll
  for (int it = 0; it < 4; ++it) {
    const int c = tid + 256 * it;          // 1024 = 128 rows x 8 segs
    const int n = c >> 3, seg = c & 7;
    *(short8*)&swb[((size_t)bh * NTOK + nb + n) * 64 + seg * 8] =
        *(const short8*)&Cs[n * 136 + 64 + seg * 8];
  }

  // ---- accumulate partials ----
  const int chunk = blockIdx.x & 15;
  float* stp = st_part + ((size_t)(chunk * 32 + bh)) * 4096;
  const int g = w * 16 + kq * 4;
#pragma unroll
  for (int j = 0; j < 4; ++j)
#pragma unroll
    for (int r = 0; r < 4; ++r)
      atomicAdd(&stp[(g + r) * 64 + j * 16 + l15], st_acc[j][r]);
  if (l15 == 0) {
    float* snp = sn_part + ((size_t)(chunk * 32 + bh)) * 64;
#pragma unroll
    for (int r = 0; r < 4; ++r)
      atomicAdd(&snp[g + r], accO[r]);
  }
}

// ---------------------------------------------------------------------------
// K3b: reduce 16 partials; st2b[b*64+g][h*64+p] = st / (sn + 1e-5)  (bf16)
__global__ __launch_bounds__(256) void k_stnorm(
    const float* __restrict__ st_part, const float* __restrict__ sn_part,
    unsigned short* __restrict__ st2b) {
  const int idx = blockIdx.x * 256 + threadIdx.x;  // 0..131071
  const int p = idx & 63, g = (idx >> 6) & 63, h = (idx >> 12) & 7, b = idx >> 15;
  const int bh = idx >> 12;
  const int gp = idx & 4095;
  float s = 0.f, sn = 0.f;
#pragma unroll
  for (int bx = 0; bx < 16; ++bx) {
    s  += st_part[((size_t)bx * 32 + bh) * 4096 + gp];
    sn += sn_part[((size_t)bx * 32 + bh) * 64 + g];
  }
  const float v = s / (sn + 1e-5f);
  st2b[(size_t)(b * 64 + g) * DIN + h * 64 + p] = f2b(v);
}

// ---------------------------------------------------------------------------
// K4: zx = st2b (256x512) @ inwb^T (1168x512). MFMA, no LDS.
__global__ __launch_bounds__(256) void k_inproj(
    const unsigned short* __restrict__ st2b, const unsigned short* __restrict__ inwb,
    float* __restrict__ zx) {
  const int tid = threadIdx.x;
  const int m0 = blockIdx.x * 64;
  const int n0 = blockIdx.y * 64;
  const int w = tid >> 6, lane = tid & 63;
  const int l15 = lane & 15, kq = lane >> 4;
  f32x4 acc[4];
#pragma unroll
  for (int j = 0; j < 4; ++j) acc[j] = (f32x4){0.f, 0.f, 0.f, 0.f};
  const int arow = m0 + w * 16 + l15;
#pragma unroll
  for (int kc = 0; kc < 16; ++kc) {
    const short8 af = *(const short8*)&st2b[(size_t)arow * DIN + kc * 32 + kq * 8];
#pragma unroll
    for (int j = 0; j < 4; ++j) {
      int brow = n0 + j * 16 + l15;
      if (brow >= DPROJ) brow = 0;
      const short8 bfr = *(const short8*)&inwb[(size_t)brow * DIN + kc * 32 + kq * 8];
      acc[j] = __builtin_amdgcn_mfma_f32_16x16x32_bf16(af, bfr, acc[j], 0, 0, 0);
    }
  }
#pragma unroll
  for (int j = 0; j < 4; ++j)
#pragma unroll
    for (int r = 0; r < 4; ++r) {
      const int m = m0 + w * 16 + kq * 4 + r;
      const int c = n0 + j * 16 + l15;
      if (c < DPROJ) zx[(size_t)m * DPROJ + c] = acc[j][r];
    }
}

// ---------------------------------------------------------------------------
// K4b: conv(k=3)+silu; dt2 / ldA2 (LOG decay).
__global__ __launch_bounds__(256) void k_prep(
    const float* __restrict__ zx, const float* __restrict__ convw, const float* __restrict__ convb,
    const float* __restrict__ dtbias, const float* __restrict__ Alog,
    float* __restrict__ xbc, float* __restrict__ dt2, float* __restrict__ ldA2) {
  const int idx = blockIdx.x * 256 + threadIdx.x;
  const int NCONV = 4 * 64 * CONVD;
  if (idx < NCONV) {
    const int c = idx % CONVD;
    const int l = (idx / CONVD) & 63;
    const int b = idx / (CONVD * 64);
    float acc = convb[c];
#pragma unroll
    for (int k = 0; k < 3; ++k) {
      const int ls = l - 2 + k;
      if (ls >= 0) acc += zx[(size_t)(b * 64 + ls) * DPROJ + DIN + c] * convw[c * 3 + k];
    }
    xbc[idx] = acc * sigmoidf_(acc);
  } else if (idx < NCONV + 8 * 64 * 8) {
    const int j = idx - NCONV;
    const int h = j & 7, l = (j >> 3) & 63, bb = j >> 9;
    float raw;
    if (bb < 4) raw = zx[(size_t)(bb * 64 + l) * DPROJ + 1152 + h];
    else        raw = zx[(size_t)((bb - 4) * 64 + (63 - l)) * DPROJ + 1160 + h];
    const float d = raw + dtbias[h];
    const float sp = (d > 20.f) ? d : log1pf(expf(d));
    dt2[j] = sp;
    ldA2[j] = sp * -expf(Alog[h]);
  }
}

// ---------------------------------------------------------------------------
// K5: SSM via decay-matrix MFMA form. One block per (bb,h).
__global__ __launch_bounds__(256) void k_ssm(
    const float* __restrict__ xbc, const float* __restrict__ dt2, const float* __restrict__ ldA2,
    float* __restrict__ ys) {
  __shared__ unsigned short s_C[64][72];
  __shared__ unsigned short s_Bm[64][72];
  __shared__ unsigned short s_X[64][72];
  __shared__ unsigned short s_G[64][72];
  __shared__ float s_L[64];
  __shared__ float s_dt[64];
  const int blk = blockIdx.x;
  const int h = blk & 7, bb = blk >> 3;
  const int b = (bb < 4) ? bb : bb - 4;
  const bool rev = bb >= 4;
  const int tid = threadIdx.x;
  const int w = tid >> 6, lane = tid & 63;
  const int l15 = lane & 15, kq = lane >> 4;
  {
    const int l = tid >> 2, part = tid & 3;
    const int t = rev ? 63 - l : l;
    const float* src = xbc + (size_t)(b * 64 + l) * CONVD + DIN + part * 32;
#pragma unroll
    for (int u = 0; u < 32; u += 4) {
      float4 v = *(const float4*)(src + u);
      const int c = part * 32 + u;
      unsigned short* dst = (c < 64) ? &s_Bm[t][c] : &s_C[t][c - 64];
      dst[0] = f2b(v.x); dst[1] = f2b(v.y); dst[2] = f2b(v.z); dst[3] = f2b(v.w);
    }
    const float* xs = xbc + (size_t)(b * 64 + l) * CONVD + h * 64 + part * 16;
#pragma unroll
    for (int u = 0; u < 16; u += 4) {
      float4 v = *(const float4*)(xs + u);
      const int p = part * 16 + u;
      s_X[p + 0][t] = f2b(v.x); s_X[p + 1][t] = f2b(v.y);
      s_X[p + 2][t] = f2b(v.z); s_X[p + 3][t] = f2b(v.w);
    }
  }
  if (w == 0) {
    const float dtv = dt2[(bb * 64 + lane) * 8 + h];
    float ld = ldA2[(bb * 64 + lane) * 8 + h];
#pragma unroll
    for (int off = 1; off < 64; off <<= 1) {
      const float o = __shfl_up(ld, off);
      if (lane >= off) ld += o;
    }
    s_L[lane] = ld;
    s_dt[lane] = dtv;
  }
  __syncthreads();
  f32x4 accS[4];
#pragma unroll
  for (int i = 0; i < 4; ++i) accS[i] = (f32x4){0.f, 0.f, 0.f, 0.f};
#pragma unroll
  for (int kw = 0; kw < 2; ++kw) {
    const short8 bfr = *(const short8*)&s_Bm[w * 16 + l15][kw * 32 + kq * 8];
#pragma unroll
    for (int i = 0; i < 4; ++i) {
      const short8 af = *(const short8*)&s_C[i * 16 + l15][kw * 32 + kq * 8];
      accS[i] = __builtin_amdgcn_mfma_f32_16x16x32_bf16(af, bfr, accS[i], 0, 0, 0);
    }
  }
  const int s_idx = w * 16 + l15;
  const float Ls = s_L[s_idx];
  const float dts = s_dt[s_idx];
#pragma unroll
  for (int i = 0; i < 4; ++i)
#pragma unroll
    for (int r = 0; r < 4; ++r) {
      const int t = i * 16 + kq * 4 + r;
      const float g = (s_idx <= t) ? accS[i][r] * expf(s_L[t] - Ls) * dts : 0.f;
      s_G[t][s_idx] = f2b(g);
    }
  __syncthreads();
  f32x4 accY[4];
#pragma unroll
  for (int i = 0; i < 4; ++i) accY[i] = (f32x4){0.f, 0.f, 0.f, 0.f};
#pragma unroll
  for (int kw = 0; kw < 2; ++kw) {
    const short8 bfr = *(const short8*)&s_X[w * 16 + l15][kw * 32 + kq * 8];
#pragma unroll
    for (int i = 0; i < 4; ++i) {
      const short8 af = *(const short8*)&s_G[i * 16 + l15][kw * 32 + kq * 8];
      accY[i] = __builtin_amdgcn_mfma_f32_16x16x32_bf16(af, bfr, accY[i], 0, 0, 0);
    }
  }
#pragma unroll
  for (int i = 0; i < 4; ++i)
#pragma unroll
    for (int r = 0; r < 4; ++r) {
      const int t = i * 16 + kq * 4 + r;
      ys[(((size_t)(bb * 64 + t) * 8 + h) << 6) + w * 16 + l15] = accY[i][r];
    }
}

// ---------------------------------------------------------------------------
// K6a: combine + gate + RMS norm; emits bf16 ygb.
__global__ __launch_bounds__(256) void k_gate(
    const float* __restrict__ ys, const float* __restrict__ xbc, const float* __restrict__ zx,
    const float* __restrict__ fcdw, const float* __restrict__ Dp,
    const float* __restrict__ normw, unsigned short* __restrict__ ygb) {
  __shared__ float red[256][9];
  __shared__ float s_xfc[8];
  const int bl = blockIdx.x;
  const int b = bl >> 6, l = bl & 63;
  const int tid = threadIdx.x;
  const float xog0 = xbc[(size_t)bl * CONVD + tid];
  const float xog1 = xbc[(size_t)bl * CONVD + 256 + tid];
#pragma unroll
  for (int h = 0; h < 8; ++h)
    red[tid][h] = xog0 * fcdw[h * DIN + tid] + xog1 * fcdw[h * DIN + 256 + tid];
  __syncthreads();
  for (int s = 128; s > 0; s >>= 1) {
    if (tid < s) {
#pragma unroll
      for (int h = 0; h < 8; ++h) red[tid][h] += red[tid + s][h];
    }
    __syncthreads();
  }
  if (tid < 8) s_xfc[tid] = red[0][tid] + Dp[tid];
  __syncthreads();
  float ygv[2];
  float sumsq = 0.f;
#pragma unroll
  for (int ci = 0; ci < 2; ++ci) {
    const int c = tid + ci * 256;
    const int h = c >> 6, p = c & 63;
    float yv = 0.f;
    if (l >= 1)  yv += ys[(((size_t)(b * 64 + (l - 1)) * 8 + h) << 6) + p];
    if (l <= 62) yv += ys[(((size_t)((4 + b) * 64 + (62 - l)) * 8 + h) << 6) + p];
    const float xog = (ci == 0) ? xog0 : xog1;
    yv += xog * s_xfc[h];
    const float z = zx[(size_t)bl * DPROJ + c];
    const float g = yv * (z * sigmoidf_(z));
    ygv[ci] = g;
    sumsq += g * g;
  }
  red[tid][0] = sumsq;
  __syncthreads();
  for (int s = 128; s > 0; s >>= 1) {
    if (tid < s) red[tid][0] += red[tid + s][0];
    __syncthreads();
  }
  const float scale = 1.f / sqrtf(red[0][0] / 512.f + 1e-5f);
#pragma unroll
  for (int ci = 0; ci < 2; ++ci) {
    const int c = tid + ci * 256;
    ygb[(size_t)bl * DIN + c] = f2b(ygv[ci] * scale * normw[c]);
  }
}

// ---------------------------------------------------------------------------
// K6b: ot = ygb (256x512) @ howb^T. Writes otT bf16 [(b,h,p)][g]. grid (4,8).
__global__ __launch_bounds__(256) void k_oproj(
    const unsigned short* __restrict__ ygb, const unsigned short* __restrict__ howb,
    unsigned short* __restrict__ otT) {
  __shared__ unsigned short Cs[64][72];
  const int tid = threadIdx.x;
  const int b = blockIdx.x;
  const int h = blockIdx.y;
  const int m0 = b * 64, n0 = h * 64;
  const int w = tid >> 6, lane = tid & 63;
  const int l15 = lane & 15, kq = lane >> 4;
  f32x4 acc[4];
#pragma unroll
  for (int j = 0; j < 4; ++j) acc[j] = (f32x4){0.f, 0.f, 0.f, 0.f};
  const int arow = m0 + w * 16 + l15;
#pragma unroll
  for (int kc = 0; kc < 16; ++kc) {
    const short8 af = *(const short8*)&ygb[(size_t)arow * DIN + kc * 32 + kq * 8];
#pragma unroll
    for (int j = 0; j < 4; ++j) {
      const int brow = n0 + j * 16 + l15;
      const short8 bfr = *(const short8*)&howb[(size_t)brow * DIN + kc * 32 + kq * 8];
      acc[j] = __builtin_amdgcn_mfma_f32_16x16x32_bf16(af, bfr, acc[j], 0, 0, 0);
    }
  }
#pragma unroll
  for (int j = 0; j < 4; ++j)
#pragma unroll
    for (int r = 0; r < 4; ++r) {
      const int g = w * 16 + kq * 4 + r;
      const int p = j * 16 + l15;
      Cs[p][g] = f2b(acc[j][r]);
    }
  __syncthreads();
#pragma unroll
  for (int it = 0; it < 2; ++it) {
    const int c = tid + 256 * it;
    const int p = c >> 3, seg = c & 7;
    *(short8*)&otT[(((size_t)(b * 8 + h) * 64 + p) << 6) + seg * 8] = *(const short8*)&Cs[p][seg * 8];
  }
}

// ---------------------------------------------------------------------------
// K7: fused mix + final. One block = 64 tokens of one b.
__global__ __launch_bounds__(256) void k_mixfinal(
    const unsigned short* __restrict__ swb, const unsigned short* __restrict__ otT,
    const unsigned short* __restrict__ outwb, const float* __restrict__ outb,
    float* __restrict__ out) {
  __shared__ unsigned short lm[33280];  // [64][520] bf16, reused as [64][260] fp32
  const int blk = blockIdx.x;           // 512 = 4 b x 128 chunks
  const int b = blk >> 7;
  const int t0 = (blk & 127) * 64;
  const int tid = threadIdx.x;
  const int w = tid >> 6, lane = tid & 63;
  const int l15 = lane & 15, kq = lane >> 4;
  // Phase 1: wave w handles heads 2w, 2w+1
#pragma unroll
  for (int hh = 0; hh < 2; ++hh) {
    const int h = w * 2 + hh;
    const int bh = b * 8 + h;
    f32x4 acc[4][4];
#pragma unroll
    for (int i = 0; i < 4; ++i)
#pragma unroll
      for (int j = 0; j < 4; ++j) acc[i][j] = (f32x4){0.f, 0.f, 0.f, 0.f};
#pragma unroll
    for (int kt = 0; kt < 2; ++kt) {
      short8 af[4], bfr[4];
#pragma unroll
      for (int i = 0; i < 4; ++i) {
        af[i]  = *(const short8*)&swb[((size_t)bh * NTOK + t0 + i * 16 + l15) * 64 + kt * 32 + kq * 8];
        bfr[i] = *(const short8*)&otT[(((size_t)bh * 64 + i * 16 + l15) << 6) + kt * 32 + kq * 8];
      }
#pragma unroll
      for (int i = 0; i < 4; ++i)
#pragma unroll
        for (int j = 0; j < 4; ++j)
          acc[i][j] = __builtin_amdgcn_mfma_f32_16x16x32_bf16(af[i], bfr[j], acc[i][j], 0, 0, 0);
    }
#pragma unroll
    for (int i = 0; i < 4; ++i)
#pragma unroll
      for (int j = 0; j < 4; ++j)
#pragma unroll
        for (int r = 0; r < 4; ++r)
          lm[(i * 16 + kq * 4 + r) * 520 + h * 64 + j * 16 + l15] = f2b(acc[i][j][r]);
  }
  __syncthreads();
  // Phase 2: wave w covers out-cols [w*64, w*64+64)
  float ob[4];
#pragma unroll
  for (int j = 0; j < 4; ++j) ob[j] = outb[w * 64 + j * 16 + l15];
  f32x4 facc[4][4];
#pragma unroll
  for (int i = 0; i < 4; ++i)
#pragma unroll
    for (int j = 0; j < 4; ++j) facc[i][j] = (f32x4){0.f, 0.f, 0.f, 0.f};
#pragma unroll
  for (int kt = 0; kt < 16; ++kt) {
    short8 af[4], bfr[4];
#pragma unroll
    for (int i = 0; i < 4; ++i) {
      af[i]  = *(const short8*)&lm[(i * 16 + l15) * 520 + kt * 32 + kq * 8];
      bfr[i] = *(const short8*)&outwb[(size_t)(w * 64 + i * 16 + l15) * 512 + kt * 32 + kq * 8];
    }
#pragma unroll
    for (int i = 0; i < 4; ++i)
#pragma unroll
      for (int j = 0; j < 4; ++j)
        facc[i][j] = __builtin_amdgcn_mfma_f32_16x16x32_bf16(af[i], bfr[j], facc[i][j], 0, 0, 0);
  }
  __syncthreads();
  float* lf = (float*)lm;  // [64][260]
#pragma unroll
  for (int i = 0; i < 4; ++i)
#pragma unroll
    for (int j = 0; j < 4; ++j)
#pragma unroll
      for (int r = 0; r < 4; ++r)
        lf[(i * 16 + kq * 4 + r) * 260 + w * 64 + j * 16 + l15] = facc[i][j][r] + ob[j];
  __syncthreads();
#pragma unroll
  for (int it = 0; it < 16; ++it) {
    const int c = tid + 256 * it;        // 4096 = 64 rows x 64 float4
    const int row = c >> 6, seg = c & 63;
    *(float4*)&out[((size_t)(b * NTOK + t0 + row)) * 256 + seg * 4] =
        *(const float4*)&lf[row * 260 + seg * 4];
  }
}

// ---------------------------------------------------------------------------
extern "C" void kernel_launch(void* const* d_in, const int* in_sizes, int n_in,
                              void* d_out, int out_size, void* d_ws, size_t ws_size,
                              hipStream_t stream) {
  const float* x      = (const float*)d_in[0];
  const float* Wfx    = (const float*)d_in[1];
  const float* bfx    = (const float*)d_in[2];
  const float* Wx     = (const float*)d_in[3];
  const float* bx     = (const float*)d_in[4];
  const float* Wslice = (const float*)d_in[5];
  const float* bslice = (const float*)d_in[6];
  const float* temp   = (const float*)d_in[7];
  const float* inw    = (const float*)d_in[8];
  const float* convw  = (const float*)d_in[9];
  const float* convb  = (const float*)d_in[10];
  const float* dtbias = (const float*)d_in[11];
  const float* Alog   = (const float*)d_in[12];
  const float* Dp     = (const float*)d_in[13];
  const float* fcdw   = (const float*)d_in[14];
  const float* normw  = (const float*)d_in[15];
  const float* how    = (const float*)d_in[16];
  const float* outw   = (const float*)d_in[17];
  const float* outb   = (const float*)d_in[18];

  unsigned short* us = (unsigned short*)d_ws;
  unsigned short* swb    = us;                   // 16,777,216
  unsigned short* wcatb  = swb + 16777216;       //    262,144
  unsigned short* outwbf = wcatb + 262144;       //    131,072
  unsigned short* otTb   = outwbf + 131072;      //    131,072
  unsigned short* inwb   = otTb + 131072;        //    598,016
  unsigned short* howb   = inwb + 598016;        //    262,144
  unsigned short* st2b   = howb + 262144;        //    131,072
  unsigned short* ygbb   = st2b + 131072;        //    131,072
  unsigned short* xbb    = ygbb + 131072;        //  8,388,608 (x as bf16)
  float* fbase = (float*)(xbb + 8388608);
  float* bcat    = fbase;                         //      1,024
  float* st_part = bcat + 1024;                   //  2,097,152 (16 partials)
  float* sn_part = st_part + 2097152;             //     32,768
  float* zx      = sn_part + 32768;               //    299,008
  float* xbc     = zx + 299008;                   //    163,840
  float* dt2     = xbc + 163840;                  //      4,096
  float* ldA2    = dt2 + 4096;                    //      4,096
  float* ysb     = ldA2 + 4096;                   //    262,144

  hipMemsetAsync(st_part, 0, (2097152 + 32768) * sizeof(float), stream);

  k_cvt     <<<dim3(5321),    256, 0, stream>>>(Wfx, Wx, outw, inw, how, bfx, bx, x,
                                                wcatb, outwbf, inwb, howb, bcat, xbb);
  k_front   <<<dim3(256, 8),  256, 0, stream>>>(xbb, wcatb, bcat, Wslice, bslice, temp,
                                                swb, st_part, sn_part);
  k_stnorm  <<<dim3(512),     256, 0, stream>>>(st_part, sn_part, st2b);
  k_inproj  <<<dim3(4, 19),   256, 0, stream>>>(st2b, inwb, zx);
  k_prep    <<<dim3(656),     256, 0, stream>>>(zx, convw, convb, dtbias, Alog, xbc, dt2, ldA2);
  k_ssm     <<<dim3(64),      256, 0, stream>>>(xbc, dt2, ldA2, ysb);
  k_gate    <<<dim3(256),     256, 0, stream>>>(ysb, xbc, zx, fcdw, Dp, normw, ygbb);
  k_oproj   <<<dim3(4, 8),    256, 0, stream>>>(ygbb, howb, otTb);
  k_mixfinal<<<dim3(512),     256, 0, stream>>>(swb, otTb, outwbf, outb, (float*)d_out);
}

// Round 6
// 255.004 us; speedup vs baseline: 1.0439x; 1.0439x over previous
//
#include <hip/hip_runtime.h>
#include <hip/hip_bf16.h>
#include <cstdint>
#include <cstddef>

#define Hh 8
#define DIN 512
#define CONVD 640
#define DPROJ 1168
#define NTOK 8192
#define DIM 256

typedef __attribute__((ext_vector_type(8))) short short8;
typedef __attribute__((ext_vector_type(4))) float f32x4;

static __device__ __forceinline__ float sigmoidf_(float x) { return 1.f / (1.f + expf(-x)); }
static __device__ __forceinline__ unsigned short f2b(float f) {
  __hip_bfloat16 h = __float2bfloat16(f);
  return *(unsigned short*)&h;
}
static __device__ __forceinline__ float b2f(unsigned short u) {
  union { unsigned int i; float f; } cv; cv.i = ((unsigned int)u) << 16; return cv.f;
}
// async global->LDS, 16B per lane. LDS dest must be linear in lane order.
static __device__ __forceinline__ void gll16(const void* g, void* l) {
  __builtin_amdgcn_global_load_lds((const __attribute__((address_space(1))) void*)g,
                                   (__attribute__((address_space(3))) void*)l, 16, 0, 0);
}

// ---------------------------------------------------------------------------
// K0: merged conversions. blocks <4096: x fp32->bf16 (8/thread).
// blocks >=4096: weights fp32->bf16 + bias concat (4/thread).
__global__ __launch_bounds__(256) void k_cvt(
    const float* __restrict__ wfx, const float* __restrict__ wx, const float* __restrict__ outw,
    const float* __restrict__ inw, const float* __restrict__ how,
    const float* __restrict__ bfx, const float* __restrict__ bx,
    const float* __restrict__ x,
    unsigned short* __restrict__ wcat, unsigned short* __restrict__ outwb,
    unsigned short* __restrict__ inwb, unsigned short* __restrict__ howb,
    float* __restrict__ bcat, unsigned short* __restrict__ xb) {
  const int blk = blockIdx.x;
  if (blk < 4096) {  // x: 4*8192*256 = 8,388,608 elems
    const int e = (blk * 256 + threadIdx.x) * 8;
    float4 v0 = *(const float4*)(x + e);
    float4 v1 = *(const float4*)(x + e + 4);
    short8 o;
    o[0] = (short)f2b(v0.x); o[1] = (short)f2b(v0.y);
    o[2] = (short)f2b(v0.z); o[3] = (short)f2b(v0.w);
    o[4] = (short)f2b(v1.x); o[5] = (short)f2b(v1.y);
    o[6] = (short)f2b(v1.z); o[7] = (short)f2b(v1.w);
    *(short8*)(xb + e) = o;
    return;
  }
  const int e = ((blk - 4096) * 256 + threadIdx.x) * 4;
  if (e >= 1253376) {
    const int i = e - 1253376;  // 0..1023
    float4 v;
    if (i < 512) v = *(const float4*)(bfx + i);
    else         v = *(const float4*)(bx + (i - 512));
    *(float4*)(bcat + i) = v;
    return;
  }
  const float* src; unsigned short* dst; int i;
  if (e < 131072)        { i = e;           src = wfx;  dst = wcat; }
  else if (e < 262144)   { i = e - 131072;  src = wx;   dst = wcat + 131072; }
  else if (e < 393216)   { i = e - 262144;  src = outw; dst = outwb; }
  else if (e < 991232)   { i = e - 393216;  src = inw;  dst = inwb; }
  else                   { i = e - 991232;  src = how;  dst = howb; }
  float4 v = *(const float4*)(src + i);
  ushort4 o;
  o.x = f2b(v.x); o.y = f2b(v.y); o.z = f2b(v.z); o.w = f2b(v.w);
  *(ushort4*)(dst + i) = o;
}

// ---------------------------------------------------------------------------
// K1: fused front GEMM. C = xb @ [W_fx|W_x]^T + bias (M=32768, N=1024, K=256).
// Coalesced global_load_lds staging, XOR-swizzled LDS, double-buffered K-loop.
// y<4: write fx cols to cb (pitch 512). y>=4: scores+softmax in-block.
__global__ __launch_bounds__(256) void k_front(
    const unsigned short* __restrict__ xb, const unsigned short* __restrict__ wcat,
    const float* __restrict__ bcat, const float* __restrict__ Wslice,
    const float* __restrict__ bslice, const float* __restrict__ temperature,
    unsigned short* __restrict__ cb, unsigned short* __restrict__ swb) {
  __shared__ unsigned short lds[32768];  // 64KB: As[2][128*64] Bs[2][128*64]; Cs reuse
  const int tid = threadIdx.x;
  const int m0 = blockIdx.x * 128;
  const int n0 = blockIdx.y * 128;
  const int w = tid >> 6, lane = tid & 63;
  const int l15 = lane & 15, kq = lane >> 4;
  const int wm = (w & 1) * 64, wn = (w >> 1) * 64;
  float bs[4];
#pragma unroll
  for (int j = 0; j < 4; ++j) bs[j] = bcat[n0 + wn + j * 16 + l15];
  f32x4 acc[4][4];
#pragma unroll
  for (int i = 0; i < 4; ++i)
#pragma unroll
    for (int j = 0; j < 4; ++j) acc[i][j] = (f32x4){0.f, 0.f, 0.f, 0.f};

  // staging: thread covers 4 chunks of A and B; coalesced (row-contiguous).
  auto stage = [&](int buf, int kt) {
    unsigned short* As = lds + buf * 8192;
    unsigned short* Bs = lds + 16384 + buf * 8192;
#pragma unroll
    for (int i = 0; i < 4; ++i) {
      const int c = tid + 256 * i;          // 0..1023
      const int m = c >> 3, kb = c & 7;
      const int kbs = (kb ^ (m & 7)) * 8;   // swizzled source chunk (same line)
      gll16(&xb[(size_t)(m0 + m) * 256 + kt + kbs], &As[c * 8]);
      gll16(&wcat[(size_t)(n0 + m) * 256 + kt + kbs], &Bs[c * 8]);
    }
  };

  stage(0, 0);
  __syncthreads();  // vmcnt(0) drain: buf0 ready
  int buf = 0;
  for (int t = 0; t < 4; ++t) {
    if (t < 3) stage(buf ^ 1, (t + 1) * 64);  // prefetch next K-slab
    const unsigned short* As = lds + buf * 8192;
    const unsigned short* Bs = lds + 16384 + buf * 8192;
#pragma unroll
    for (int kw = 0; kw < 2; ++kw) {
      short8 af[4], bfr[4];
#pragma unroll
      for (int i = 0; i < 4; ++i) {
        const int rm = wm + i * 16 + l15;
        af[i]  = *(const short8*)&As[rm * 64 + ((kw * 32 + kq * 8) ^ ((rm & 7) << 3))];
        const int rn = wn + i * 16 + l15;
        bfr[i] = *(const short8*)&Bs[rn * 64 + ((kw * 32 + kq * 8) ^ ((rn & 7) << 3))];
      }
#pragma unroll
      for (int i = 0; i < 4; ++i)
#pragma unroll
        for (int j = 0; j < 4; ++j)
          acc[i][j] = __builtin_amdgcn_mfma_f32_16x16x32_bf16(af[i], bfr[j], acc[i][j], 0, 0, 0);
    }
    __syncthreads();  // drains vmcnt(0) (prefetch landed) + read-fence for buf
    buf ^= 1;
  }
  // epilogue: C (+bias) -> Cs [128][136]
  unsigned short* Cs = lds;
#pragma unroll
  for (int i = 0; i < 4; ++i)
#pragma unroll
    for (int j = 0; j < 4; ++j)
#pragma unroll
      for (int r = 0; r < 4; ++r) {
        const int m = wm + i * 16 + kq * 4 + r;
        const int n = wn + j * 16 + l15;
        Cs[m * 136 + n] = f2b(acc[i][j][r] + bs[j]);
      }
  __syncthreads();
  if (blockIdx.y < 4) {
    // fx: coalesced stores, cb pitch 512. Full 128x128 tile (16 segs of 8).
#pragma unroll
    for (int it = 0; it < 8; ++it) {
      const int c = tid + 256 * it;
      const int m = c >> 4, seg = c & 15;
      *(short8*)&cb[(size_t)(m0 + m) * 512 + n0 + seg * 8] = *(const short8*)&Cs[m * 136 + seg * 8];
    }
    return;
  }
  // ---- fused scores + softmax for two heads ----
  const int h0 = (n0 - 512) >> 6;  // first head of this col-tile
  const int bidx = m0 >> 13, nb = m0 & (NTOK - 1);
  short8 sbfr[2][4];
#pragma unroll
  for (int kt = 0; kt < 2; ++kt)
#pragma unroll
    for (int j = 0; j < 4; ++j) {
      const float* wp = Wslice + (j * 16 + l15) * 64 + kt * 32 + kq * 8;
      short8 t;
#pragma unroll
      for (int u = 0; u < 8; ++u) t[u] = (short)f2b(wp[u]);
      sbfr[kt][j] = t;
    }
  float sbs[4];
#pragma unroll
  for (int j = 0; j < 4; ++j) sbs[j] = bslice[j * 16 + l15];
  f32x4 sacc[2][2][4];
#pragma unroll
  for (int hl = 0; hl < 2; ++hl)
#pragma unroll
    for (int i = 0; i < 2; ++i)
#pragma unroll
      for (int j = 0; j < 4; ++j) sacc[hl][i][j] = (f32x4){0.f, 0.f, 0.f, 0.f};
#pragma unroll
  for (int hl = 0; hl < 2; ++hl)
#pragma unroll
    for (int kt = 0; kt < 2; ++kt) {
      short8 af[2];
#pragma unroll
      for (int i = 0; i < 2; ++i)
        af[i] = *(const short8*)&Cs[(w * 32 + i * 16 + l15) * 136 + hl * 64 + kt * 32 + kq * 8];
#pragma unroll
      for (int i = 0; i < 2; ++i)
#pragma unroll
        for (int j = 0; j < 4; ++j)
          sacc[hl][i][j] = __builtin_amdgcn_mfma_f32_16x16x32_bf16(af[i], sbfr[kt][j], sacc[hl][i][j], 0, 0, 0);
    }
  __syncthreads();  // all reads of Cs done; reuse Cs for softmax output
#pragma unroll
  for (int hl = 0; hl < 2; ++hl) {
    const float invt = 1.f / fmaxf(temperature[h0 + hl], 1e-6f);
#pragma unroll
    for (int i = 0; i < 2; ++i)
#pragma unroll
      for (int r = 0; r < 4; ++r) {
        float v[4];
        float m = -1e30f;
#pragma unroll
        for (int j = 0; j < 4; ++j) { v[j] = (sacc[hl][i][j][r] + sbs[j]) * invt; m = fmaxf(m, v[j]); }
#pragma unroll
        for (int off = 8; off; off >>= 1) m = fmaxf(m, __shfl_xor(m, off));
        float s = 0.f;
#pragma unroll
        for (int j = 0; j < 4; ++j) { v[j] = expf(v[j] - m); s += v[j]; }
#pragma unroll
        for (int off = 8; off; off >>= 1) s += __shfl_xor(s, off);
        const float inv = 1.f / s;
        const int row = w * 32 + i * 16 + kq * 4 + r;
#pragma unroll
        for (int j = 0; j < 4; ++j) Cs[row * 136 + hl * 64 + j * 16 + l15] = f2b(v[j] * inv);
      }
  }
  __syncthreads();
#pragma unroll
  for (int it = 0; it < 8; ++it) {
    const int c = tid + 256 * it;          // 2048 = 2 heads x 128 rows x 8 segs
    const int head = c >> 10, row = (c >> 3) & 127, seg = c & 7;
    *(short8*)&swb[((size_t)(bidx * 8 + h0 + head) * NTOK + nb + row) * 64 + seg * 8] =
        *(const short8*)&Cs[row * 136 + head * 64 + seg * 8];
  }
}

// ---------------------------------------------------------------------------
// K3: st_part[bx][bh][g][p] = sum_n sw[n,g]*fx[n,p] over 1024-token range.
// sn via ones-MFMA. XOR-swizzled transpose LDS; plain stores (privatized).
__global__ __launch_bounds__(256) void k_st(
    const unsigned short* __restrict__ swb, const unsigned short* __restrict__ cb,
    float* __restrict__ st_part, float* __restrict__ sn_part) {
  __shared__ unsigned short swT[64][136];
  __shared__ unsigned short fxT[64][136];
  const int tid = threadIdx.x;
  const int bh = blockIdx.y;
  const int b = bh >> 3, h = bh & 7;
  const int nbase = blockIdx.x * 1024;
  const int w = tid >> 6, lane = tid & 63;
  const int l15 = lane & 15, kq = lane >> 4;
  short8 ones;
#pragma unroll
  for (int u = 0; u < 8; ++u) ones[u] = (short)0x3F80;  // bf16 1.0
  f32x4 acc[4], accO[4];
#pragma unroll
  for (int i = 0; i < 4; ++i) {
    acc[i] = (f32x4){0.f, 0.f, 0.f, 0.f};
    accO[i] = (f32x4){0.f, 0.f, 0.f, 0.f};
  }
  for (int nc = 0; nc < 8; ++nc) {
    const int n0 = nbase + nc * 128;
#pragma unroll
    for (int i = 0; i < 4; ++i) {
      const int c = tid + 256 * i, n = c >> 3, gc = c & 7;
      short8 sv = *(const short8*)&swb[((size_t)bh * NTOK + n0 + n) * 64 + gc * 8];
      short8 fv = *(const short8*)&cb[((size_t)(b * NTOK) + n0 + n) * 512 + h * 64 + gc * 8];
      const int csw = n ^ (gc << 4);  // swizzle: row>>3 == gc for rows gc*8+u
#pragma unroll
      for (int u = 0; u < 8; ++u) {
        swT[gc * 8 + u][csw] = (unsigned short)sv[u];
        fxT[gc * 8 + u][csw] = (unsigned short)fv[u];
      }
    }
    __syncthreads();
#pragma unroll
    for (int kw = 0; kw < 4; ++kw) {
      const int brow = w * 16 + l15;
      const short8 bfr = *(const short8*)&fxT[brow][(kw * 32 + kq * 8) ^ ((brow >> 3) << 4)];
#pragma unroll
      for (int mi = 0; mi < 4; ++mi) {
        const int arow = mi * 16 + l15;
        const short8 af = *(const short8*)&swT[arow][(kw * 32 + kq * 8) ^ ((arow >> 3) << 4)];
        acc[mi] = __builtin_amdgcn_mfma_f32_16x16x32_bf16(af, bfr, acc[mi], 0, 0, 0);
        if (w == 0)
          accO[mi] = __builtin_amdgcn_mfma_f32_16x16x32_bf16(af, ones, accO[mi], 0, 0, 0);
      }
    }
    __syncthreads();
  }
  float* stp = st_part + ((size_t)blockIdx.x * 32 + bh) * 4096;
#pragma unroll
  for (int mi = 0; mi < 4; ++mi)
#pragma unroll
    for (int r = 0; r < 4; ++r)
      stp[(mi * 16 + kq * 4 + r) * 64 + w * 16 + l15] = acc[mi][r];
  if (w == 0 && l15 == 0) {
    float* snp = sn_part + ((size_t)blockIdx.x * 32 + bh) * 64;
#pragma unroll
    for (int mi = 0; mi < 4; ++mi)
#pragma unroll
      for (int r = 0; r < 4; ++r)
        snp[mi * 16 + kq * 4 + r] = accO[mi][r];
  }
}

// ---------------------------------------------------------------------------
// K3b: reduce 8 partials; st2b[b*64+g][h*64+p] = st / (sn + 1e-5)  (bf16)
__global__ __launch_bounds__(256) void k_stnorm(
    const float* __restrict__ st_part, const float* __restrict__ sn_part,
    unsigned short* __restrict__ st2b) {
  const int idx = blockIdx.x * 256 + threadIdx.x;  // 0..131071
  const int p = idx & 63, g = (idx >> 6) & 63, h = (idx >> 12) & 7, b = idx >> 15;
  const int bh = idx >> 12;
  const int gp = idx & 4095;
  float s = 0.f, sn = 0.f;
#pragma unroll
  for (int bx = 0; bx < 8; ++bx) {
    s  += st_part[((size_t)bx * 32 + bh) * 4096 + gp];
    sn += sn_part[((size_t)bx * 32 + bh) * 64 + g];
  }
  const float v = s / (sn + 1e-5f);
  st2b[(size_t)(b * 64 + g) * DIN + h * 64 + p] = f2b(v);
}

// ---------------------------------------------------------------------------
// K4: zx = st2b (256x512) @ inwb^T (1168x512). MFMA, no LDS.
__global__ __launch_bounds__(256) void k_inproj(
    const unsigned short* __restrict__ st2b, const unsigned short* __restrict__ inwb,
    float* __restrict__ zx) {
  const int tid = threadIdx.x;
  const int m0 = blockIdx.x * 64;
  const int n0 = blockIdx.y * 64;
  const int w = tid >> 6, lane = tid & 63;
  const int l15 = lane & 15, kq = lane >> 4;
  f32x4 acc[4];
#pragma unroll
  for (int j = 0; j < 4; ++j) acc[j] = (f32x4){0.f, 0.f, 0.f, 0.f};
  const int arow = m0 + w * 16 + l15;
#pragma unroll
  for (int kc = 0; kc < 16; ++kc) {
    const short8 af = *(const short8*)&st2b[(size_t)arow * DIN + kc * 32 + kq * 8];
#pragma unroll
    for (int j = 0; j < 4; ++j) {
      int brow = n0 + j * 16 + l15;
      if (brow >= DPROJ) brow = 0;
      const short8 bfr = *(const short8*)&inwb[(size_t)brow * DIN + kc * 32 + kq * 8];
      acc[j] = __builtin_amdgcn_mfma_f32_16x16x32_bf16(af, bfr, acc[j], 0, 0, 0);
    }
  }
#pragma unroll
  for (int j = 0; j < 4; ++j)
#pragma unroll
    for (int r = 0; r < 4; ++r) {
      const int m = m0 + w * 16 + kq * 4 + r;
      const int c = n0 + j * 16 + l15;
      if (c < DPROJ) zx[(size_t)m * DPROJ + c] = acc[j][r];
    }
}

// ---------------------------------------------------------------------------
// K4b: conv(k=3)+silu; dt2 / ldA2 (LOG decay).
__global__ __launch_bounds__(256) void k_prep(
    const float* __restrict__ zx, const float* __restrict__ convw, const float* __restrict__ convb,
    const float* __restrict__ dtbias, const float* __restrict__ Alog,
    float* __restrict__ xbc, float* __restrict__ dt2, float* __restrict__ ldA2) {
  const int idx = blockIdx.x * 256 + threadIdx.x;
  const int NCONV = 4 * 64 * CONVD;
  if (idx < NCONV) {
    const int c = idx % CONVD;
    const int l = (idx / CONVD) & 63;
    const int b = idx / (CONVD * 64);
    float acc = convb[c];
#pragma unroll
    for (int k = 0; k < 3; ++k) {
      const int ls = l - 2 + k;
      if (ls >= 0) acc += zx[(size_t)(b * 64 + ls) * DPROJ + DIN + c] * convw[c * 3 + k];
    }
    xbc[idx] = acc * sigmoidf_(acc);
  } else if (idx < NCONV + 8 * 64 * 8) {
    const int j = idx - NCONV;
    const int h = j & 7, l = (j >> 3) & 63, bb = j >> 9;
    float raw;
    if (bb < 4) raw = zx[(size_t)(bb * 64 + l) * DPROJ + 1152 + h];
    else        raw = zx[(size_t)((bb - 4) * 64 + (63 - l)) * DPROJ + 1160 + h];
    const float d = raw + dtbias[h];
    const float sp = (d > 20.f) ? d : log1pf(expf(d));
    dt2[j] = sp;
    ldA2[j] = sp * -expf(Alog[h]);
  }
}

// ---------------------------------------------------------------------------
// K5: SSM via decay-matrix MFMA form. One block per (bb,h).
__global__ __launch_bounds__(256) void k_ssm(
    const float* __restrict__ xbc, const float* __restrict__ dt2, const float* __restrict__ ldA2,
    float* __restrict__ ys) {
  __shared__ unsigned short s_C[64][72];
  __shared__ unsigned short s_Bm[64][72];
  __shared__ unsigned short s_X[64][72];
  __shared__ unsigned short s_G[64][72];
  __shared__ float s_L[64];
  __shared__ float s_dt[64];
  const int blk = blockIdx.x;
  const int h = blk & 7, bb = blk >> 3;
  const int b = (bb < 4) ? bb : bb - 4;
  const bool rev = bb >= 4;
  const int tid = threadIdx.x;
  const int w = tid >> 6, lane = tid & 63;
  const int l15 = lane & 15, kq = lane >> 4;
  {
    const int l = tid >> 2, part = tid & 3;
    const int t = rev ? 63 - l : l;
    const float* src = xbc + (size_t)(b * 64 + l) * CONVD + DIN + part * 32;
#pragma unroll
    for (int u = 0; u < 32; u += 4) {
      float4 v = *(const float4*)(src + u);
      const int c = part * 32 + u;
      unsigned short* dst = (c < 64) ? &s_Bm[t][c] : &s_C[t][c - 64];
      dst[0] = f2b(v.x); dst[1] = f2b(v.y); dst[2] = f2b(v.z); dst[3] = f2b(v.w);
    }
    const float* xs = xbc + (size_t)(b * 64 + l) * CONVD + h * 64 + part * 16;
#pragma unroll
    for (int u = 0; u < 16; u += 4) {
      float4 v = *(const float4*)(xs + u);
      const int p = part * 16 + u;
      s_X[p + 0][t] = f2b(v.x); s_X[p + 1][t] = f2b(v.y);
      s_X[p + 2][t] = f2b(v.z); s_X[p + 3][t] = f2b(v.w);
    }
  }
  if (w == 0) {
    const float dtv = dt2[(bb * 64 + lane) * 8 + h];
    float ld = ldA2[(bb * 64 + lane) * 8 + h];
#pragma unroll
    for (int off = 1; off < 64; off <<= 1) {
      const float o = __shfl_up(ld, off);
      if (lane >= off) ld += o;
    }
    s_L[lane] = ld;
    s_dt[lane] = dtv;
  }
  __syncthreads();
  f32x4 accS[4];
#pragma unroll
  for (int i = 0; i < 4; ++i) accS[i] = (f32x4){0.f, 0.f, 0.f, 0.f};
#pragma unroll
  for (int kw = 0; kw < 2; ++kw) {
    const short8 bfr = *(const short8*)&s_Bm[w * 16 + l15][kw * 32 + kq * 8];
#pragma unroll
    for (int i = 0; i < 4; ++i) {
      const short8 af = *(const short8*)&s_C[i * 16 + l15][kw * 32 + kq * 8];
      accS[i] = __builtin_amdgcn_mfma_f32_16x16x32_bf16(af, bfr, accS[i], 0, 0, 0);
    }
  }
  const int s_idx = w * 16 + l15;
  const float Ls = s_L[s_idx];
  const float dts = s_dt[s_idx];
#pragma unroll
  for (int i = 0; i < 4; ++i)
#pragma unroll
    for (int r = 0; r < 4; ++r) {
      const int t = i * 16 + kq * 4 + r;
      const float g = (s_idx <= t) ? accS[i][r] * expf(s_L[t] - Ls) * dts : 0.f;
      s_G[t][s_idx] = f2b(g);
    }
  __syncthreads();
  f32x4 accY[4];
#pragma unroll
  for (int i = 0; i < 4; ++i) accY[i] = (f32x4){0.f, 0.f, 0.f, 0.f};
#pragma unroll
  for (int kw = 0; kw < 2; ++kw) {
    const short8 bfr = *(const short8*)&s_X[w * 16 + l15][kw * 32 + kq * 8];
#pragma unroll
    for (int i = 0; i < 4; ++i) {
      const short8 af = *(const short8*)&s_G[i * 16 + l15][kw * 32 + kq * 8];
      accY[i] = __builtin_amdgcn_mfma_f32_16x16x32_bf16(af, bfr, accY[i], 0, 0, 0);
    }
  }
#pragma unroll
  for (int i = 0; i < 4; ++i)
#pragma unroll
    for (int r = 0; r < 4; ++r) {
      const int t = i * 16 + kq * 4 + r;
      ys[(((size_t)(bb * 64 + t) * 8 + h) << 6) + w * 16 + l15] = accY[i][r];
    }
}

// ---------------------------------------------------------------------------
// K6a: combine + gate + RMS norm; emits bf16 ygb. Shuffle-based reductions.
__global__ __launch_bounds__(256) void k_gate(
    const float* __restrict__ ys, const float* __restrict__ xbc, const float* __restrict__ zx,
    const float* __restrict__ fcdw, const float* __restrict__ Dp,
    const float* __restrict__ normw, unsigned short* __restrict__ ygb) {
  __shared__ float xw[4][8];
  __shared__ float xs[4];
  __shared__ float s_xfc[8];
  const int bl = blockIdx.x;
  const int b = bl >> 6, l = bl & 63;
  const int tid = threadIdx.x;
  const int w = tid >> 6, lane = tid & 63;
  const float xog0 = xbc[(size_t)bl * CONVD + tid];
  const float xog1 = xbc[(size_t)bl * CONVD + 256 + tid];
  float p8[8];
#pragma unroll
  for (int h = 0; h < 8; ++h)
    p8[h] = xog0 * fcdw[h * DIN + tid] + xog1 * fcdw[h * DIN + 256 + tid];
#pragma unroll
  for (int off = 32; off; off >>= 1)
#pragma unroll
    for (int h = 0; h < 8; ++h) p8[h] += __shfl_xor(p8[h], off);
  if (lane == 0) {
#pragma unroll
    for (int h = 0; h < 8; ++h) xw[w][h] = p8[h];
  }
  __syncthreads();
  if (tid < 8) s_xfc[tid] = xw[0][tid] + xw[1][tid] + xw[2][tid] + xw[3][tid] + Dp[tid];
  __syncthreads();
  float ygv[2];
  float sumsq = 0.f;
#pragma unroll
  for (int ci = 0; ci < 2; ++ci) {
    const int c = tid + ci * 256;
    const int h = c >> 6, p = c & 63;
    float yv = 0.f;
    if (l >= 1)  yv += ys[(((size_t)(b * 64 + (l - 1)) * 8 + h) << 6) + p];
    if (l <= 62) yv += ys[(((size_t)((4 + b) * 64 + (62 - l)) * 8 + h) << 6) + p];
    const float xog = (ci == 0) ? xog0 : xog1;
    yv += xog * s_xfc[h];
    const float z = zx[(size_t)bl * DPROJ + c];
    const float g = yv * (z * sigmoidf_(z));
    ygv[ci] = g;
    sumsq += g * g;
  }
#pragma unroll
  for (int off = 32; off; off >>= 1) sumsq += __shfl_xor(sumsq, off);
  if (lane == 0) xs[w] = sumsq;
  __syncthreads();
  const float tot = xs[0] + xs[1] + xs[2] + xs[3];
  const float scale = 1.f / sqrtf(tot / 512.f + 1e-5f);
#pragma unroll
  for (int ci = 0; ci < 2; ++ci) {
    const int c = tid + ci * 256;
    ygb[(size_t)bl * DIN + c] = f2b(ygv[ci] * scale * normw[c]);
  }
}

// ---------------------------------------------------------------------------
// K6b: ot = ygb (256x512) @ howb^T. Writes otT bf16 [(b,h,p)][g]. grid (4,8).
__global__ __launch_bounds__(256) void k_oproj(
    const unsigned short* __restrict__ ygb, const unsigned short* __restrict__ howb,
    unsigned short* __restrict__ otT) {
  __shared__ unsigned short Cs[64][72];
  const int tid = threadIdx.x;
  const int b = blockIdx.x;
  const int h = blockIdx.y;
  const int m0 = b * 64, n0 = h * 64;
  const int w = tid >> 6, lane = tid & 63;
  const int l15 = lane & 15, kq = lane >> 4;
  f32x4 acc[4];
#pragma unroll
  for (int j = 0; j < 4; ++j) acc[j] = (f32x4){0.f, 0.f, 0.f, 0.f};
  const int arow = m0 + w * 16 + l15;
#pragma unroll
  for (int kc = 0; kc < 16; ++kc) {
    const short8 af = *(const short8*)&ygb[(size_t)arow * DIN + kc * 32 + kq * 8];
#pragma unroll
    for (int j = 0; j < 4; ++j) {
      const int brow = n0 + j * 16 + l15;
      const short8 bfr = *(const short8*)&howb[(size_t)brow * DIN + kc * 32 + kq * 8];
      acc[j] = __builtin_amdgcn_mfma_f32_16x16x32_bf16(af, bfr, acc[j], 0, 0, 0);
    }
  }
#pragma unroll
  for (int j = 0; j < 4; ++j)
#pragma unroll
    for (int r = 0; r < 4; ++r) {
      const int g = w * 16 + kq * 4 + r;
      const int p = j * 16 + l15;
      Cs[p][g] = f2b(acc[j][r]);
    }
  __syncthreads();
#pragma unroll
  for (int it = 0; it < 2; ++it) {
    const int c = tid + 256 * it;
    const int p = c >> 3, seg = c & 7;
    *(short8*)&otT[(((size_t)(b * 8 + h) * 64 + p) << 6) + seg * 8] = *(const short8*)&Cs[p][seg * 8];
  }
}

// ---------------------------------------------------------------------------
// K7: fused mix + final. One block = 64 tokens of one b.
__global__ __launch_bounds__(256) void k_mixfinal(
    const unsigned short* __restrict__ swb, const unsigned short* __restrict__ otT,
    const unsigned short* __restrict__ outwb, const float* __restrict__ outb,
    float* __restrict__ out) {
  __shared__ unsigned short lm[33280];  // [64][520] bf16, reused as [64][260] fp32
  const int blk = blockIdx.x;           // 512 = 4 b x 128 chunks
  const int b = blk >> 7;
  const int t0 = (blk & 127) * 64;
  const int tid = threadIdx.x;
  const int w = tid >> 6, lane = tid & 63;
  const int l15 = lane & 15, kq = lane >> 4;
  // Phase 1: wave w handles heads 2w, 2w+1
#pragma unroll
  for (int hh = 0; hh < 2; ++hh) {
    const int h = w * 2 + hh;
    const int bh = b * 8 + h;
    f32x4 acc[4][4];
#pragma unroll
    for (int i = 0; i < 4; ++i)
#pragma unroll
      for (int j = 0; j < 4; ++j) acc[i][j] = (f32x4){0.f, 0.f, 0.f, 0.f};
#pragma unroll
    for (int kt = 0; kt < 2; ++kt) {
      short8 af[4], bfr[4];
#pragma unroll
      for (int i = 0; i < 4; ++i) {
        af[i]  = *(const short8*)&swb[((size_t)bh * NTOK + t0 + i * 16 + l15) * 64 + kt * 32 + kq * 8];
        bfr[i] = *(const short8*)&otT[(((size_t)bh * 64 + i * 16 + l15) << 6) + kt * 32 + kq * 8];
      }
#pragma unroll
      for (int i = 0; i < 4; ++i)
#pragma unroll
        for (int j = 0; j < 4; ++j)
          acc[i][j] = __builtin_amdgcn_mfma_f32_16x16x32_bf16(af[i], bfr[j], acc[i][j], 0, 0, 0);
    }
#pragma unroll
    for (int i = 0; i < 4; ++i)
#pragma unroll
      for (int j = 0; j < 4; ++j)
#pragma unroll
        for (int r = 0; r < 4; ++r)
          lm[(i * 16 + kq * 4 + r) * 520 + h * 64 + j * 16 + l15] = f2b(acc[i][j][r]);
  }
  __syncthreads();
  // Phase 2: wave w covers out-cols [w*64, w*64+64)
  float ob[4];
#pragma unroll
  for (int j = 0; j < 4; ++j) ob[j] = outb[w * 64 + j * 16 + l15];
  f32x4 facc[4][4];
#pragma unroll
  for (int i = 0; i < 4; ++i)
#pragma unroll
    for (int j = 0; j < 4; ++j) facc[i][j] = (f32x4){0.f, 0.f, 0.f, 0.f};
#pragma unroll
  for (int kt = 0; kt < 16; ++kt) {
    short8 af[4], bfr[4];
#pragma unroll
    for (int i = 0; i < 4; ++i) {
      af[i]  = *(const short8*)&lm[(i * 16 + l15) * 520 + kt * 32 + kq * 8];
      bfr[i] = *(const short8*)&outwb[(size_t)(w * 64 + i * 16 + l15) * 512 + kt * 32 + kq * 8];
    }
#pragma unroll
    for (int i = 0; i < 4; ++i)
#pragma unroll
      for (int j = 0; j < 4; ++j)
        facc[i][j] = __builtin_amdgcn_mfma_f32_16x16x32_bf16(af[i], bfr[j], facc[i][j], 0, 0, 0);
  }
  __syncthreads();
  float* lf = (float*)lm;  // [64][260]
#pragma unroll
  for (int i = 0; i < 4; ++i)
#pragma unroll
    for (int j = 0; j < 4; ++j)
#pragma unroll
      for (int r = 0; r < 4; ++r)
        lf[(i * 16 + kq * 4 + r) * 260 + w * 64 + j * 16 + l15] = facc[i][j][r] + ob[j];
  __syncthreads();
#pragma unroll
  for (int it = 0; it < 16; ++it) {
    const int c = tid + 256 * it;        // 4096 = 64 rows x 64 float4
    const int row = c >> 6, seg = c & 63;
    *(float4*)&out[((size_t)(b * NTOK + t0 + row)) * 256 + seg * 4] =
        *(const float4*)&lf[row * 260 + seg * 4];
  }
}

// ---------------------------------------------------------------------------
extern "C" void kernel_launch(void* const* d_in, const int* in_sizes, int n_in,
                              void* d_out, int out_size, void* d_ws, size_t ws_size,
                              hipStream_t stream) {
  const float* x      = (const float*)d_in[0];
  const float* Wfx    = (const float*)d_in[1];
  const float* bfx    = (const float*)d_in[2];
  const float* Wx     = (const float*)d_in[3];
  const float* bx     = (const float*)d_in[4];
  const float* Wslice = (const float*)d_in[5];
  const float* bslice = (const float*)d_in[6];
  const float* temp   = (const float*)d_in[7];
  const float* inw    = (const float*)d_in[8];
  const float* convw  = (const float*)d_in[9];
  const float* convb  = (const float*)d_in[10];
  const float* dtbias = (const float*)d_in[11];
  const float* Alog   = (const float*)d_in[12];
  const float* Dp     = (const float*)d_in[13];
  const float* fcdw   = (const float*)d_in[14];
  const float* normw  = (const float*)d_in[15];
  const float* how    = (const float*)d_in[16];
  const float* outw   = (const float*)d_in[17];
  const float* outb   = (const float*)d_in[18];

  unsigned short* us = (unsigned short*)d_ws;
  unsigned short* cb     = us;                   // 16,777,216 (fx token-major, pitch 512)
  unsigned short* swb    = cb + 16777216;        // 16,777,216
  unsigned short* wcatb  = swb + 16777216;       //    262,144
  unsigned short* outwbf = wcatb + 262144;       //    131,072
  unsigned short* otTb   = outwbf + 131072;      //    131,072
  unsigned short* inwb   = otTb + 131072;        //    598,016
  unsigned short* howb   = inwb + 598016;        //    262,144
  unsigned short* st2b   = howb + 262144;        //    131,072
  unsigned short* ygbb   = st2b + 131072;        //    131,072
  unsigned short* xbb    = ygbb + 131072;        //  8,388,608 (x as bf16)
  float* fbase = (float*)(xbb + 8388608);
  float* bcat    = fbase;                         //      1,024
  float* st_part = bcat + 1024;                   //  1,048,576 (8 partials)
  float* sn_part = st_part + 1048576;             //     16,384
  float* zx      = sn_part + 16384;               //    299,008
  float* xbc     = zx + 299008;                   //    163,840
  float* dt2     = xbc + 163840;                  //      4,096
  float* ldA2    = dt2 + 4096;                    //      4,096
  float* ysb     = ldA2 + 4096;                   //    262,144

  k_cvt     <<<dim3(5321),    256, 0, stream>>>(Wfx, Wx, outw, inw, how, bfx, bx, x,
                                                wcatb, outwbf, inwb, howb, bcat, xbb);
  k_front   <<<dim3(256, 8),  256, 0, stream>>>(xbb, wcatb, bcat, Wslice, bslice, temp, cb, swb);
  k_st      <<<dim3(8, 32),   256, 0, stream>>>(swb, cb, st_part, sn_part);
  k_stnorm  <<<dim3(512),     256, 0, stream>>>(st_part, sn_part, st2b);
  k_inproj  <<<dim3(4, 19),   256, 0, stream>>>(st2b, inwb, zx);
  k_prep    <<<dim3(656),     256, 0, stream>>>(zx, convw, convb, dtbias, Alog, xbc, dt2, ldA2);
  k_ssm     <<<dim3(64),      256, 0, stream>>>(xbc, dt2, ldA2, ysb);
  k_gate    <<<dim3(256),     256, 0, stream>>>(ysb, xbc, zx, fcdw, Dp, normw, ygbb);
  k_oproj   <<<dim3(4, 8),    256, 0, stream>>>(ygbb, howb, otTb);
  k_mixfinal<<<dim3(512),     256, 0, stream>>>(swb, otTb, outwbf, outb, (float*)d_out);
}

// Round 7
// 249.884 us; speedup vs baseline: 1.0653x; 1.0205x over previous
//
#include <hip/hip_runtime.h>
#include <hip/hip_bf16.h>
#include <cstdint>
#include <cstddef>

#define Hh 8
#define DIN 512
#define CONVD 640
#define DPROJ 1168
#define NTOK 8192
#define DIM 256

typedef __attribute__((ext_vector_type(8))) short short8;
typedef __attribute__((ext_vector_type(4))) float f32x4;

static __device__ __forceinline__ float sigmoidf_(float x) { return 1.f / (1.f + expf(-x)); }
static __device__ __forceinline__ unsigned short f2b(float f) {
  __hip_bfloat16 h = __float2bfloat16(f);
  return *(unsigned short*)&h;
}
static __device__ __forceinline__ float b2f(unsigned short u) {
  union { unsigned int i; float f; } cv; cv.i = ((unsigned int)u) << 16; return cv.f;
}
// async global->LDS, 16B per lane. LDS dest must be linear in lane order.
static __device__ __forceinline__ void gll16(const void* g, void* l) {
  __builtin_amdgcn_global_load_lds((const __attribute__((address_space(1))) void*)g,
                                   (__attribute__((address_space(3))) void*)l, 16, 0, 0);
}

// ---------------------------------------------------------------------------
// K0: merged conversions. blocks <4096: x fp32->bf16 (8/thread).
// blocks >=4096: weights fp32->bf16 + bias concat (4/thread).
__global__ __launch_bounds__(256) void k_cvt(
    const float* __restrict__ wfx, const float* __restrict__ wx, const float* __restrict__ outw,
    const float* __restrict__ inw, const float* __restrict__ how,
    const float* __restrict__ bfx, const float* __restrict__ bx,
    const float* __restrict__ x,
    unsigned short* __restrict__ wcat, unsigned short* __restrict__ outwb,
    unsigned short* __restrict__ inwb, unsigned short* __restrict__ howb,
    float* __restrict__ bcat, unsigned short* __restrict__ xb) {
  const int blk = blockIdx.x;
  if (blk < 4096) {  // x: 4*8192*256 = 8,388,608 elems
    const int e = (blk * 256 + threadIdx.x) * 8;
    float4 v0 = *(const float4*)(x + e);
    float4 v1 = *(const float4*)(x + e + 4);
    short8 o;
    o[0] = (short)f2b(v0.x); o[1] = (short)f2b(v0.y);
    o[2] = (short)f2b(v0.z); o[3] = (short)f2b(v0.w);
    o[4] = (short)f2b(v1.x); o[5] = (short)f2b(v1.y);
    o[6] = (short)f2b(v1.z); o[7] = (short)f2b(v1.w);
    *(short8*)(xb + e) = o;
    return;
  }
  const int e = ((blk - 4096) * 256 + threadIdx.x) * 4;
  if (e >= 1253376) {
    const int i = e - 1253376;  // 0..1023
    float4 v;
    if (i < 512) v = *(const float4*)(bfx + i);
    else         v = *(const float4*)(bx + (i - 512));
    *(float4*)(bcat + i) = v;
    return;
  }
  const float* src; unsigned short* dst; int i;
  if (e < 131072)        { i = e;           src = wfx;  dst = wcat; }
  else if (e < 262144)   { i = e - 131072;  src = wx;   dst = wcat + 131072; }
  else if (e < 393216)   { i = e - 262144;  src = outw; dst = outwb; }
  else if (e < 991232)   { i = e - 393216;  src = inw;  dst = inwb; }
  else                   { i = e - 991232;  src = how;  dst = howb; }
  float4 v = *(const float4*)(src + i);
  ushort4 o;
  o.x = f2b(v.x); o.y = f2b(v.y); o.z = f2b(v.z); o.w = f2b(v.w);
  *(ushort4*)(dst + i) = o;
}

// ---------------------------------------------------------------------------
// K1: fused front GEMM. C = xb @ [W_fx|W_x]^T + bias (M=32768, N=1024, K=256).
// Coalesced global_load_lds staging, XOR-swizzled LDS, double-buffered K-loop.
// y<4: write fx cols to cb (pitch 512). y>=4: scores+softmax in-block.
__global__ __launch_bounds__(256) void k_front(
    const unsigned short* __restrict__ xb, const unsigned short* __restrict__ wcat,
    const float* __restrict__ bcat, const float* __restrict__ Wslice,
    const float* __restrict__ bslice, const float* __restrict__ temperature,
    unsigned short* __restrict__ cb, unsigned short* __restrict__ swb) {
  __shared__ unsigned short lds[32768];  // 64KB: As[2][128*64] Bs[2][128*64]; Cs reuse
  const int tid = threadIdx.x;
  const int m0 = blockIdx.x * 128;
  const int n0 = blockIdx.y * 128;
  const int w = tid >> 6, lane = tid & 63;
  const int l15 = lane & 15, kq = lane >> 4;
  const int wm = (w & 1) * 64, wn = (w >> 1) * 64;
  float bs[4];
#pragma unroll
  for (int j = 0; j < 4; ++j) bs[j] = bcat[n0 + wn + j * 16 + l15];
  f32x4 acc[4][4];
#pragma unroll
  for (int i = 0; i < 4; ++i)
#pragma unroll
    for (int j = 0; j < 4; ++j) acc[i][j] = (f32x4){0.f, 0.f, 0.f, 0.f};

  // staging: thread covers 4 chunks of A and B; coalesced (row-contiguous).
  auto stage = [&](int buf, int kt) {
    unsigned short* As = lds + buf * 8192;
    unsigned short* Bs = lds + 16384 + buf * 8192;
#pragma unroll
    for (int i = 0; i < 4; ++i) {
      const int c = tid + 256 * i;          // 0..1023
      const int m = c >> 3, kb = c & 7;
      const int kbs = (kb ^ (m & 7)) * 8;   // swizzled source chunk (same line)
      gll16(&xb[(size_t)(m0 + m) * 256 + kt + kbs], &As[c * 8]);
      gll16(&wcat[(size_t)(n0 + m) * 256 + kt + kbs], &Bs[c * 8]);
    }
  };

  stage(0, 0);
  __syncthreads();  // vmcnt(0) drain: buf0 ready
  int buf = 0;
  for (int t = 0; t < 4; ++t) {
    if (t < 3) stage(buf ^ 1, (t + 1) * 64);  // prefetch next K-slab
    const unsigned short* As = lds + buf * 8192;
    const unsigned short* Bs = lds + 16384 + buf * 8192;
#pragma unroll
    for (int kw = 0; kw < 2; ++kw) {
      short8 af[4], bfr[4];
#pragma unroll
      for (int i = 0; i < 4; ++i) {
        const int rm = wm + i * 16 + l15;
        af[i]  = *(const short8*)&As[rm * 64 + ((kw * 32 + kq * 8) ^ ((rm & 7) << 3))];
        const int rn = wn + i * 16 + l15;
        bfr[i] = *(const short8*)&Bs[rn * 64 + ((kw * 32 + kq * 8) ^ ((rn & 7) << 3))];
      }
#pragma unroll
      for (int i = 0; i < 4; ++i)
#pragma unroll
        for (int j = 0; j < 4; ++j)
          acc[i][j] = __builtin_amdgcn_mfma_f32_16x16x32_bf16(af[i], bfr[j], acc[i][j], 0, 0, 0);
    }
    __syncthreads();  // drains vmcnt(0) (prefetch landed) + read-fence for buf
    buf ^= 1;
  }
  // epilogue: C (+bias) -> Cs [128][136]
  unsigned short* Cs = lds;
#pragma unroll
  for (int i = 0; i < 4; ++i)
#pragma unroll
    for (int j = 0; j < 4; ++j)
#pragma unroll
      for (int r = 0; r < 4; ++r) {
        const int m = wm + i * 16 + kq * 4 + r;
        const int n = wn + j * 16 + l15;
        Cs[m * 136 + n] = f2b(acc[i][j][r] + bs[j]);
      }
  __syncthreads();
  if (blockIdx.y < 4) {
    // fx: coalesced stores, cb pitch 512. Full 128x128 tile (16 segs of 8).
#pragma unroll
    for (int it = 0; it < 8; ++it) {
      const int c = tid + 256 * it;
      const int m = c >> 4, seg = c & 15;
      *(short8*)&cb[(size_t)(m0 + m) * 512 + n0 + seg * 8] = *(const short8*)&Cs[m * 136 + seg * 8];
    }
    return;
  }
  // ---- fused scores + softmax for two heads ----
  const int h0 = (blockIdx.y - 4) * 2;  // first head of this col-tile
  const int bidx = m0 >> 13, nb = m0 & (NTOK - 1);
  short8 sbfr[2][4];
#pragma unroll
  for (int kt = 0; kt < 2; ++kt)
#pragma unroll
    for (int j = 0; j < 4; ++j) {
      const float* wp = Wslice + (j * 16 + l15) * 64 + kt * 32 + kq * 8;
      short8 t;
#pragma unroll
      for (int u = 0; u < 8; ++u) t[u] = (short)f2b(wp[u]);
      sbfr[kt][j] = t;
    }
  float sbs[4];
#pragma unroll
  for (int j = 0; j < 4; ++j) sbs[j] = bslice[j * 16 + l15];
  f32x4 sacc[2][2][4];
#pragma unroll
  for (int hl = 0; hl < 2; ++hl)
#pragma unroll
    for (int i = 0; i < 2; ++i)
#pragma unroll
      for (int j = 0; j < 4; ++j) sacc[hl][i][j] = (f32x4){0.f, 0.f, 0.f, 0.f};
#pragma unroll
  for (int hl = 0; hl < 2; ++hl)
#pragma unroll
    for (int kt = 0; kt < 2; ++kt) {
      short8 af[2];
#pragma unroll
      for (int i = 0; i < 2; ++i)
        af[i] = *(const short8*)&Cs[(w * 32 + i * 16 + l15) * 136 + hl * 64 + kt * 32 + kq * 8];
#pragma unroll
      for (int i = 0; i < 2; ++i)
#pragma unroll
        for (int j = 0; j < 4; ++j)
          sacc[hl][i][j] = __builtin_amdgcn_mfma_f32_16x16x32_bf16(af[i], sbfr[kt][j], sacc[hl][i][j], 0, 0, 0);
    }
  __syncthreads();  // all reads of Cs done; reuse Cs for softmax output
#pragma unroll
  for (int hl = 0; hl < 2; ++hl) {
    const float invt = 1.f / fmaxf(temperature[h0 + hl], 1e-6f);
#pragma unroll
    for (int i = 0; i < 2; ++i)
#pragma unroll
      for (int r = 0; r < 4; ++r) {
        float v[4];
        float m = -1e30f;
#pragma unroll
        for (int j = 0; j < 4; ++j) { v[j] = (sacc[hl][i][j][r] + sbs[j]) * invt; m = fmaxf(m, v[j]); }
#pragma unroll
        for (int off = 8; off; off >>= 1) m = fmaxf(m, __shfl_xor(m, off));
        float s = 0.f;
#pragma unroll
        for (int j = 0; j < 4; ++j) { v[j] = expf(v[j] - m); s += v[j]; }
#pragma unroll
        for (int off = 8; off; off >>= 1) s += __shfl_xor(s, off);
        const float inv = 1.f / s;
        const int row = w * 32 + i * 16 + kq * 4 + r;
#pragma unroll
        for (int j = 0; j < 4; ++j) Cs[row * 136 + hl * 64 + j * 16 + l15] = f2b(v[j] * inv);
      }
  }
  __syncthreads();
#pragma unroll
  for (int it = 0; it < 8; ++it) {
    const int c = tid + 256 * it;          // 2048 = 2 heads x 128 rows x 8 segs
    const int head = c >> 10, row = (c >> 3) & 127, seg = c & 7;
    *(short8*)&swb[((size_t)(bidx * 8 + h0 + head) * NTOK + nb + row) * 64 + seg * 8] =
        *(const short8*)&Cs[row * 136 + head * 64 + seg * 8];
  }
}

// ---------------------------------------------------------------------------
// K3: st_part[bx][bh][g][p] = sum_n sw[n,g]*fx[n,p] over 512-token range.
// sn via ones-MFMA. XOR-swizzled transpose LDS; plain stores (privatized).
__global__ __launch_bounds__(256) void k_st(
    const unsigned short* __restrict__ swb, const unsigned short* __restrict__ cb,
    float* __restrict__ st_part, float* __restrict__ sn_part) {
  __shared__ unsigned short swT[64][136];
  __shared__ unsigned short fxT[64][136];
  const int tid = threadIdx.x;
  const int bh = blockIdx.y;
  const int b = bh >> 3, h = bh & 7;
  const int nbase = blockIdx.x * 512;
  const int w = tid >> 6, lane = tid & 63;
  const int l15 = lane & 15, kq = lane >> 4;
  short8 ones;
#pragma unroll
  for (int u = 0; u < 8; ++u) ones[u] = (short)0x3F80;  // bf16 1.0
  f32x4 acc[4], accO[4];
#pragma unroll
  for (int i = 0; i < 4; ++i) {
    acc[i] = (f32x4){0.f, 0.f, 0.f, 0.f};
    accO[i] = (f32x4){0.f, 0.f, 0.f, 0.f};
  }
  for (int nc = 0; nc < 4; ++nc) {
    const int n0 = nbase + nc * 128;
#pragma unroll
    for (int i = 0; i < 4; ++i) {
      const int c = tid + 256 * i, n = c >> 3, gc = c & 7;
      short8 sv = *(const short8*)&swb[((size_t)bh * NTOK + n0 + n) * 64 + gc * 8];
      short8 fv = *(const short8*)&cb[((size_t)(b * NTOK) + n0 + n) * 512 + h * 64 + gc * 8];
      const int csw = n ^ (gc << 4);  // swizzle: row>>3 == gc for rows gc*8+u
#pragma unroll
      for (int u = 0; u < 8; ++u) {
        swT[gc * 8 + u][csw] = (unsigned short)sv[u];
        fxT[gc * 8 + u][csw] = (unsigned short)fv[u];
      }
    }
    __syncthreads();
#pragma unroll
    for (int kw = 0; kw < 4; ++kw) {
      const int brow = w * 16 + l15;
      const short8 bfr = *(const short8*)&fxT[brow][(kw * 32 + kq * 8) ^ ((brow >> 3) << 4)];
#pragma unroll
      for (int mi = 0; mi < 4; ++mi) {
        const int arow = mi * 16 + l15;
        const short8 af = *(const short8*)&swT[arow][(kw * 32 + kq * 8) ^ ((arow >> 3) << 4)];
        acc[mi] = __builtin_amdgcn_mfma_f32_16x16x32_bf16(af, bfr, acc[mi], 0, 0, 0);
        if (w == 0)
          accO[mi] = __builtin_amdgcn_mfma_f32_16x16x32_bf16(af, ones, accO[mi], 0, 0, 0);
      }
    }
    __syncthreads();
  }
  float* stp = st_part + ((size_t)blockIdx.x * 32 + bh) * 4096;
#pragma unroll
  for (int mi = 0; mi < 4; ++mi)
#pragma unroll
    for (int r = 0; r < 4; ++r)
      stp[(mi * 16 + kq * 4 + r) * 64 + w * 16 + l15] = acc[mi][r];
  if (w == 0 && l15 == 0) {
    float* snp = sn_part + ((size_t)blockIdx.x * 32 + bh) * 64;
#pragma unroll
    for (int mi = 0; mi < 4; ++mi)
#pragma unroll
      for (int r = 0; r < 4; ++r)
        snp[mi * 16 + kq * 4 + r] = accO[mi][r];
  }
}

// ---------------------------------------------------------------------------
// K3b: reduce 16 partials; st2b[b*64+g][h*64+p] = st / (sn + 1e-5)  (bf16)
__global__ __launch_bounds__(256) void k_stnorm(
    const float* __restrict__ st_part, const float* __restrict__ sn_part,
    unsigned short* __restrict__ st2b) {
  const int idx = blockIdx.x * 256 + threadIdx.x;  // 0..131071
  const int p = idx & 63, g = (idx >> 6) & 63, h = (idx >> 12) & 7, b = idx >> 15;
  const int bh = idx >> 12;
  const int gp = idx & 4095;
  float s = 0.f, sn = 0.f;
#pragma unroll
  for (int bx = 0; bx < 16; ++bx) {
    s  += st_part[((size_t)bx * 32 + bh) * 4096 + gp];
    sn += sn_part[((size_t)bx * 32 + bh) * 64 + g];
  }
  const float v = s / (sn + 1e-5f);
  st2b[(size_t)(b * 64 + g) * DIN + h * 64 + p] = f2b(v);
}

// ---------------------------------------------------------------------------
// K4: zx = st2b (256x512) @ inwb^T (1168x512), fused with conv+silu+dt prep.
// grid (4,19): m-tile = one batch's 64 tokens. y<8: store zx (gate's z cols).
// y in 8..17: conv channels (y-8)*64..+63 computed in-LDS -> xbc (no zx store).
// y==18: dt2/ldA2 from cols 1152..1167.
__global__ __launch_bounds__(256) void k_inproj(
    const unsigned short* __restrict__ st2b, const unsigned short* __restrict__ inwb,
    const float* __restrict__ convw, const float* __restrict__ convb,
    const float* __restrict__ dtbias, const float* __restrict__ Alog,
    float* __restrict__ zx, float* __restrict__ xbc,
    float* __restrict__ dt2, float* __restrict__ ldA2) {
  __shared__ float zs[64][65];
  const int tid = threadIdx.x;
  const int b = blockIdx.x;
  const int m0 = b * 64;
  const int y = blockIdx.y;
  const int n0 = y * 64;
  const int w = tid >> 6, lane = tid & 63;
  const int l15 = lane & 15, kq = lane >> 4;
  f32x4 acc[4];
#pragma unroll
  for (int j = 0; j < 4; ++j) acc[j] = (f32x4){0.f, 0.f, 0.f, 0.f};
  const int arow = m0 + w * 16 + l15;
#pragma unroll
  for (int kc = 0; kc < 16; ++kc) {
    const short8 af = *(const short8*)&st2b[(size_t)arow * DIN + kc * 32 + kq * 8];
#pragma unroll
    for (int j = 0; j < 4; ++j) {
      int brow = n0 + j * 16 + l15;
      if (brow >= DPROJ) brow = 0;
      const short8 bfr = *(const short8*)&inwb[(size_t)brow * DIN + kc * 32 + kq * 8];
      acc[j] = __builtin_amdgcn_mfma_f32_16x16x32_bf16(af, bfr, acc[j], 0, 0, 0);
    }
  }
  if (y < 8) {
    // z-region: store zx (consumed by k_gate).
#pragma unroll
    for (int j = 0; j < 4; ++j)
#pragma unroll
      for (int r = 0; r < 4; ++r) {
        const int m = m0 + w * 16 + kq * 4 + r;
        const int c = n0 + j * 16 + l15;
        zx[(size_t)m * DPROJ + c] = acc[j][r];
      }
    return;
  }
  // stage tile in LDS for conv / dt
#pragma unroll
  for (int j = 0; j < 4; ++j)
#pragma unroll
    for (int r = 0; r < 4; ++r)
      zs[w * 16 + kq * 4 + r][j * 16 + l15] = acc[j][r];
  __syncthreads();
  if (y < 18) {
    // conv(k=3, causal within the 64-token batch) + silu -> xbc
    const int cc0 = (y - 8) * 64;
    const int l = tid >> 2, q = tid & 3;
#pragma unroll
    for (int u = 0; u < 16; u += 4) {
      float4 o;
      float* op = &o.x;
#pragma unroll
      for (int v = 0; v < 4; ++v) {
        const int lc = q * 16 + u + v;
        const int cc = cc0 + lc;
        float a = convb[cc];
#pragma unroll
        for (int k = 0; k < 3; ++k) {
          const int ls = l - 2 + k;
          if (ls >= 0) a += zs[ls][lc] * convw[cc * 3 + k];
        }
        op[v] = a * sigmoidf_(a);
      }
      *(float4*)&xbc[((size_t)(b * 64 + l)) * CONVD + cc0 + q * 16 + u] = o;
    }
    return;
  }
  // y == 18: dt2 / ldA2 from cols 1152..1167 (local 0..15)
#pragma unroll
  for (int u = 0; u < 4; ++u) {
    const int e = tid + 256 * u;         // 0..1023
    const int h = e & 7, l = (e >> 3) & 63, dir = e >> 9;
    const float raw = (dir == 0) ? zs[l][h] : zs[63 - l][8 + h];
    const float d = raw + dtbias[h];
    const float sp = (d > 20.f) ? d : log1pf(expf(d));
    const int j = ((dir ? (4 + b) : b) * 64 + l) * 8 + h;
    dt2[j] = sp;
    ldA2[j] = sp * -expf(Alog[h]);
  }
}

// ---------------------------------------------------------------------------
// K5: SSM via decay-matrix MFMA form. One block per (bb,h).
__global__ __launch_bounds__(256) void k_ssm(
    const float* __restrict__ xbc, const float* __restrict__ dt2, const float* __restrict__ ldA2,
    float* __restrict__ ys) {
  __shared__ unsigned short s_C[64][72];
  __shared__ unsigned short s_Bm[64][72];
  __shared__ unsigned short s_X[64][72];
  __shared__ unsigned short s_G[64][72];
  __shared__ float s_L[64];
  __shared__ float s_dt[64];
  const int blk = blockIdx.x;
  const int h = blk & 7, bb = blk >> 3;
  const int b = (bb < 4) ? bb : bb - 4;
  const bool rev = bb >= 4;
  const int tid = threadIdx.x;
  const int w = tid >> 6, lane = tid & 63;
  const int l15 = lane & 15, kq = lane >> 4;
  {
    const int l = tid >> 2, part = tid & 3;
    const int t = rev ? 63 - l : l;
    const float* src = xbc + (size_t)(b * 64 + l) * CONVD + DIN + part * 32;
#pragma unroll
    for (int u = 0; u < 32; u += 4) {
      float4 v = *(const float4*)(src + u);
      const int c = part * 32 + u;
      unsigned short* dst = (c < 64) ? &s_Bm[t][c] : &s_C[t][c - 64];
      dst[0] = f2b(v.x); dst[1] = f2b(v.y); dst[2] = f2b(v.z); dst[3] = f2b(v.w);
    }
    const float* xs = xbc + (size_t)(b * 64 + l) * CONVD + h * 64 + part * 16;
#pragma unroll
    for (int u = 0; u < 16; u += 4) {
      float4 v = *(const float4*)(xs + u);
      const int p = part * 16 + u;
      s_X[p + 0][t] = f2b(v.x); s_X[p + 1][t] = f2b(v.y);
      s_X[p + 2][t] = f2b(v.z); s_X[p + 3][t] = f2b(v.w);
    }
  }
  if (w == 0) {
    const float dtv = dt2[(bb * 64 + lane) * 8 + h];
    float ld = ldA2[(bb * 64 + lane) * 8 + h];
#pragma unroll
    for (int off = 1; off < 64; off <<= 1) {
      const float o = __shfl_up(ld, off);
      if (lane >= off) ld += o;
    }
    s_L[lane] = ld;
    s_dt[lane] = dtv;
  }
  __syncthreads();
  f32x4 accS[4];
#pragma unroll
  for (int i = 0; i < 4; ++i) accS[i] = (f32x4){0.f, 0.f, 0.f, 0.f};
#pragma unroll
  for (int kw = 0; kw < 2; ++kw) {
    const short8 bfr = *(const short8*)&s_Bm[w * 16 + l15][kw * 32 + kq * 8];
#pragma unroll
    for (int i = 0; i < 4; ++i) {
      const short8 af = *(const short8*)&s_C[i * 16 + l15][kw * 32 + kq * 8];
      accS[i] = __builtin_amdgcn_mfma_f32_16x16x32_bf16(af, bfr, accS[i], 0, 0, 0);
    }
  }
  const int s_idx = w * 16 + l15;
  const float Ls = s_L[s_idx];
  const float dts = s_dt[s_idx];
#pragma unroll
  for (int i = 0; i < 4; ++i)
#pragma unroll
    for (int r = 0; r < 4; ++r) {
      const int t = i * 16 + kq * 4 + r;
      const float g = (s_idx <= t) ? accS[i][r] * expf(s_L[t] - Ls) * dts : 0.f;
      s_G[t][s_idx] = f2b(g);
    }
  __syncthreads();
  f32x4 accY[4];
#pragma unroll
  for (int i = 0; i < 4; ++i) accY[i] = (f32x4){0.f, 0.f, 0.f, 0.f};
#pragma unroll
  for (int kw = 0; kw < 2; ++kw) {
    const short8 bfr = *(const short8*)&s_X[w * 16 + l15][kw * 32 + kq * 8];
#pragma unroll
    for (int i = 0; i < 4; ++i) {
      const short8 af = *(const short8*)&s_G[i * 16 + l15][kw * 32 + kq * 8];
      accY[i] = __builtin_amdgcn_mfma_f32_16x16x32_bf16(af, bfr, accY[i], 0, 0, 0);
    }
  }
#pragma unroll
  for (int i = 0; i < 4; ++i)
#pragma unroll
    for (int r = 0; r < 4; ++r) {
      const int t = i * 16 + kq * 4 + r;
      ys[(((size_t)(bb * 64 + t) * 8 + h) << 6) + w * 16 + l15] = accY[i][r];
    }
}

// ---------------------------------------------------------------------------
// K6a: combine + gate + RMS norm; emits bf16 ygb. Shuffle-based reductions.
__global__ __launch_bounds__(256) void k_gate(
    const float* __restrict__ ys, const float* __restrict__ xbc, const float* __restrict__ zx,
    const float* __restrict__ fcdw, const float* __restrict__ Dp,
    const float* __restrict__ normw, unsigned short* __restrict__ ygb) {
  __shared__ float xw[4][8];
  __shared__ float xs[4];
  __shared__ float s_xfc[8];
  const int bl = blockIdx.x;
  const int b = bl >> 6, l = bl & 63;
  const int tid = threadIdx.x;
  const int w = tid >> 6, lane = tid & 63;
  const float xog0 = xbc[(size_t)bl * CONVD + tid];
  const float xog1 = xbc[(size_t)bl * CONVD + 256 + tid];
  float p8[8];
#pragma unroll
  for (int h = 0; h < 8; ++h)
    p8[h] = xog0 * fcdw[h * DIN + tid] + xog1 * fcdw[h * DIN + 256 + tid];
#pragma unroll
  for (int off = 32; off; off >>= 1)
#pragma unroll
    for (int h = 0; h < 8; ++h) p8[h] += __shfl_xor(p8[h], off);
  if (lane == 0) {
#pragma unroll
    for (int h = 0; h < 8; ++h) xw[w][h] = p8[h];
  }
  __syncthreads();
  if (tid < 8) s_xfc[tid] = xw[0][tid] + xw[1][tid] + xw[2][tid] + xw[3][tid] + Dp[tid];
  __syncthreads();
  float ygv[2];
  float sumsq = 0.f;
#pragma unroll
  for (int ci = 0; ci < 2; ++ci) {
    const int c = tid + ci * 256;
    const int h = c >> 6, p = c & 63;
    float yv = 0.f;
    if (l >= 1)  yv += ys[(((size_t)(b * 64 + (l - 1)) * 8 + h) << 6) + p];
    if (l <= 62) yv += ys[(((size_t)((4 + b) * 64 + (62 - l)) * 8 + h) << 6) + p];
    const float xog = (ci == 0) ? xog0 : xog1;
    yv += xog * s_xfc[h];
    const float z = zx[(size_t)bl * DPROJ + c];
    const float g = yv * (z * sigmoidf_(z));
    ygv[ci] = g;
    sumsq += g * g;
  }
#pragma unroll
  for (int off = 32; off; off >>= 1) sumsq += __shfl_xor(sumsq, off);
  if (lane == 0) xs[w] = sumsq;
  __syncthreads();
  const float tot = xs[0] + xs[1] + xs[2] + xs[3];
  const float scale = 1.f / sqrtf(tot / 512.f + 1e-5f);
#pragma unroll
  for (int ci = 0; ci < 2; ++ci) {
    const int c = tid + ci * 256;
    ygb[(size_t)bl * DIN + c] = f2b(ygv[ci] * scale * normw[c]);
  }
}

// ---------------------------------------------------------------------------
// K6b: ot = ygb (256x512) @ howb^T. Writes otT bf16 [(b,h,p)][g]. grid (4,8).
__global__ __launch_bounds__(256) void k_oproj(
    const unsigned short* __restrict__ ygb, const unsigned short* __restrict__ howb,
    unsigned short* __restrict__ otT) {
  __shared__ unsigned short Cs[64][72];
  const int tid = threadIdx.x;
  const int b = blockIdx.x;
  const int h = blockIdx.y;
  const int m0 = b * 64, n0 = h * 64;
  const int w = tid >> 6, lane = tid & 63;
  const int l15 = lane & 15, kq = lane >> 4;
  f32x4 acc[4];
#pragma unroll
  for (int j = 0; j < 4; ++j) acc[j] = (f32x4){0.f, 0.f, 0.f, 0.f};
  const int arow = m0 + w * 16 + l15;
#pragma unroll
  for (int kc = 0; kc < 16; ++kc) {
    const short8 af = *(const short8*)&ygb[(size_t)arow * DIN + kc * 32 + kq * 8];
#pragma unroll
    for (int j = 0; j < 4; ++j) {
      const int brow = n0 + j * 16 + l15;
      const short8 bfr = *(const short8*)&howb[(size_t)brow * DIN + kc * 32 + kq * 8];
      acc[j] = __builtin_amdgcn_mfma_f32_16x16x32_bf16(af, bfr, acc[j], 0, 0, 0);
    }
  }
#pragma unroll
  for (int j = 0; j < 4; ++j)
#pragma unroll
    for (int r = 0; r < 4; ++r) {
      const int g = w * 16 + kq * 4 + r;
      const int p = j * 16 + l15;
      Cs[p][g] = f2b(acc[j][r]);
    }
  __syncthreads();
#pragma unroll
  for (int it = 0; it < 2; ++it) {
    const int c = tid + 256 * it;
    const int p = c >> 3, seg = c & 7;
    *(short8*)&otT[(((size_t)(b * 8 + h) * 64 + p) << 6) + seg * 8] = *(const short8*)&Cs[p][seg * 8];
  }
}

// ---------------------------------------------------------------------------
// K7: fused mix + final. One block = 64 tokens of one b.
__global__ __launch_bounds__(256) void k_mixfinal(
    const unsigned short* __restrict__ swb, const unsigned short* __restrict__ otT,
    const unsigned short* __restrict__ outwb, const float* __restrict__ outb,
    float* __restrict__ out) {
  __shared__ unsigned short lm[33280];  // [64][520] bf16, reused as [64][260] fp32
  const int blk = blockIdx.x;           // 512 = 4 b x 128 chunks
  const int b = blk >> 7;
  const int t0 = (blk & 127) * 64;
  const int tid = threadIdx.x;
  const int w = tid >> 6, lane = tid & 63;
  const int l15 = lane & 15, kq = lane >> 4;
  // Phase 1: wave w handles heads 2w, 2w+1
#pragma unroll
  for (int hh = 0; hh < 2; ++hh) {
    const int h = w * 2 + hh;
    const int bh = b * 8 + h;
    f32x4 acc[4][4];
#pragma unroll
    for (int i = 0; i < 4; ++i)
#pragma unroll
      for (int j = 0; j < 4; ++j) acc[i][j] = (f32x4){0.f, 0.f, 0.f, 0.f};
#pragma unroll
    for (int kt = 0; kt < 2; ++kt) {
      short8 af[4], bfr[4];
#pragma unroll
      for (int i = 0; i < 4; ++i) {
        af[i]  = *(const short8*)&swb[((size_t)bh * NTOK + t0 + i * 16 + l15) * 64 + kt * 32 + kq * 8];
        bfr[i] = *(const short8*)&otT[(((size_t)bh * 64 + i * 16 + l15) << 6) + kt * 32 + kq * 8];
      }
#pragma unroll
      for (int i = 0; i < 4; ++i)
#pragma unroll
        for (int j = 0; j < 4; ++j)
          acc[i][j] = __builtin_amdgcn_mfma_f32_16x16x32_bf16(af[i], bfr[j], acc[i][j], 0, 0, 0);
    }
#pragma unroll
    for (int i = 0; i < 4; ++i)
#pragma unroll
      for (int j = 0; j < 4; ++j)
#pragma unroll
        for (int r = 0; r < 4; ++r)
          lm[(i * 16 + kq * 4 + r) * 520 + h * 64 + j * 16 + l15] = f2b(acc[i][j][r]);
  }
  __syncthreads();
  // Phase 2: wave w covers out-cols [w*64, w*64+64)
  float ob[4];
#pragma unroll
  for (int j = 0; j < 4; ++j) ob[j] = outb[w * 64 + j * 16 + l15];
  f32x4 facc[4][4];
#pragma unroll
  for (int i = 0; i < 4; ++i)
#pragma unroll
    for (int j = 0; j < 4; ++j) facc[i][j] = (f32x4){0.f, 0.f, 0.f, 0.f};
#pragma unroll
  for (int kt = 0; kt < 16; ++kt) {
    short8 af[4], bfr[4];
#pragma unroll
    for (int i = 0; i < 4; ++i) {
      af[i]  = *(const short8*)&lm[(i * 16 + l15) * 520 + kt * 32 + kq * 8];
      bfr[i] = *(const short8*)&outwb[(size_t)(w * 64 + i * 16 + l15) * 512 + kt * 32 + kq * 8];
    }
#pragma unroll
    for (int i = 0; i < 4; ++i)
#pragma unroll
      for (int j = 0; j < 4; ++j)
        facc[i][j] = __builtin_amdgcn_mfma_f32_16x16x32_bf16(af[i], bfr[j], facc[i][j], 0, 0, 0);
  }
  __syncthreads();
  float* lf = (float*)lm;  // [64][260]
#pragma unroll
  for (int i = 0; i < 4; ++i)
#pragma unroll
    for (int j = 0; j < 4; ++j)
#pragma unroll
      for (int r = 0; r < 4; ++r)
        lf[(i * 16 + kq * 4 + r) * 260 + w * 64 + j * 16 + l15] = facc[i][j][r] + ob[j];
  __syncthreads();
#pragma unroll
  for (int it = 0; it < 16; ++it) {
    const int c = tid + 256 * it;        // 4096 = 64 rows x 64 float4
    const int row = c >> 6, seg = c & 63;
    *(float4*)&out[((size_t)(b * NTOK + t0 + row)) * 256 + seg * 4] =
        *(const float4*)&lf[row * 260 + seg * 4];
  }
}

// ---------------------------------------------------------------------------
extern "C" void kernel_launch(void* const* d_in, const int* in_sizes, int n_in,
                              void* d_out, int out_size, void* d_ws, size_t ws_size,
                              hipStream_t stream) {
  const float* x      = (const float*)d_in[0];
  const float* Wfx    = (const float*)d_in[1];
  const float* bfx    = (const float*)d_in[2];
  const float* Wx     = (const float*)d_in[3];
  const float* bx     = (const float*)d_in[4];
  const float* Wslice = (const float*)d_in[5];
  const float* bslice = (const float*)d_in[6];
  const float* temp   = (const float*)d_in[7];
  const float* inw    = (const float*)d_in[8];
  const float* convw  = (const float*)d_in[9];
  const float* convb  = (const float*)d_in[10];
  const float* dtbias = (const float*)d_in[11];
  const float* Alog   = (const float*)d_in[12];
  const float* Dp     = (const float*)d_in[13];
  const float* fcdw   = (const float*)d_in[14];
  const float* normw  = (const float*)d_in[15];
  const float* how    = (const float*)d_in[16];
  const float* outw   = (const float*)d_in[17];
  const float* outb   = (const float*)d_in[18];

  unsigned short* us = (unsigned short*)d_ws;
  unsigned short* cb     = us;                   // 16,777,216 (fx token-major, pitch 512)
  unsigned short* swb    = cb + 16777216;        // 16,777,216
  unsigned short* wcatb  = swb + 16777216;       //    262,144
  unsigned short* outwbf = wcatb + 262144;       //    131,072
  unsigned short* otTb   = outwbf + 131072;      //    131,072
  unsigned short* inwb   = otTb + 131072;        //    598,016
  unsigned short* howb   = inwb + 598016;        //    262,144
  unsigned short* st2b   = howb + 262144;        //    131,072
  unsigned short* ygbb   = st2b + 131072;        //    131,072
  unsigned short* xbb    = ygbb + 131072;        //  8,388,608 (x as bf16)
  float* fbase = (float*)(xbb + 8388608);
  float* bcat    = fbase;                         //      1,024
  float* st_part = bcat + 1024;                   //  2,097,152 (16 partials)
  float* sn_part = st_part + 2097152;             //     32,768
  float* zx      = sn_part + 32768;               //    299,008
  float* xbc     = zx + 299008;                   //    163,840
  float* dt2     = xbc + 163840;                  //      4,096
  float* ldA2    = dt2 + 4096;                    //      4,096
  float* ysb     = ldA2 + 4096;                   //    262,144

  k_cvt     <<<dim3(5321),    256, 0, stream>>>(Wfx, Wx, outw, inw, how, bfx, bx, x,
                                                wcatb, outwbf, inwb, howb, bcat, xbb);
  k_front   <<<dim3(256, 8),  256, 0, stream>>>(xbb, wcatb, bcat, Wslice, bslice, temp, cb, swb);
  k_st      <<<dim3(16, 32),  256, 0, stream>>>(swb, cb, st_part, sn_part);
  k_stnorm  <<<dim3(512),     256, 0, stream>>>(st_part, sn_part, st2b);
  k_inproj  <<<dim3(4, 19),   256, 0, stream>>>(st2b, inwb, convw, convb, dtbias, Alog,
                                                zx, xbc, dt2, ldA2);
  k_ssm     <<<dim3(64),      256, 0, stream>>>(xbc, dt2, ldA2, ysb);
  k_gate    <<<dim3(256),     256, 0, stream>>>(ysb, xbc, zx, fcdw, Dp, normw, ygbb);
  k_oproj   <<<dim3(4, 8),    256, 0, stream>>>(ygbb, howb, otTb);
  k_mixfinal<<<dim3(512),     256, 0, stream>>>(swb, otTb, outwbf, outb, (float*)d_out);
}